// Round 8
// baseline (890.413 us; speedup 1.0000x reference)
//
#include <hip/hip_runtime.h>
#include <hip/hip_bf16.h>
#include <math.h>

// Problem dims
#define BB 8
#define TT 4096
#define DD 256
#define INNER 512
#define SS 16
#define MTOK (BB*TT)          // 32768 tokens
#define NCODE 240

#define SCAN_NC 64
#define SCAN_L  64            // TT / SCAN_NC

typedef unsigned short u16;
typedef unsigned int   u32;
typedef __attribute__((ext_vector_type(8))) short short8;   // 8 bf16 (4 VGPRs)
typedef __attribute__((ext_vector_type(4))) float f32x4;    // 4 fp32 acc

__device__ __forceinline__ float sigmoidf_(float x) { return 1.f / (1.f + expf(-x)); }
__device__ __forceinline__ float siluf_(float x)    { return x / (1.f + expf(-x)); }
__device__ __forceinline__ float geluf_(float x) {
    float x3 = x * x * x;
    return 0.5f * x * (1.f + tanhf(0.7978845608028654f * (x + 0.044715f * x3)));
}
__device__ __forceinline__ float softplusf_(float x) {
    return fmaxf(x, 0.f) + log1pf(expf(-fabsf(x)));
}

// bf16 round-to-nearest-even helpers
__device__ __forceinline__ u16 f2bf(float v) {
    u32 u = __float_as_uint(v);
    u32 r = (u + 0x7FFFu + ((u >> 16) & 1u)) >> 16;
    return (u16)r;
}
__device__ __forceinline__ float bf2f(u16 h) {
    return __uint_as_float(((u32)h) << 16);
}

__device__ __forceinline__ void gload16(const void* g, void* l) {
    __builtin_amdgcn_global_load_lds((const __attribute__((address_space(1))) u32*)g,
                                     (__attribute__((address_space(3))) u32*)l, 16, 0, 0);
}

// ---------------------------------------------------------------------------
// Split-bf16 MFMA GEMM: C[M,N] = act(A[M,K] @ W[K,N] + bias)
// MODE: 0=fused in_proj+conv (cols<512 silu -> XC planes; cols>=512 -> GATE f32)
//       2=dt+bc  (cols<512 softplus -> DT f32; cols 512..543 -> BC f32)
//       4=out    (y f32 + y planes)
//       5=head   (gelu -> F1 f32 [M,128])
// CT = number of 128-wide column tiles (N/128).
// XCD-aware mapping (T1): 1-D grid of 256*CT blocks; xcd = i&7 owns rows
// [xcd*32, xcd*32+32); within an XCD, col varies fastest.
// ---------------------------------------------------------------------------
template<int MODE, int CT>
__global__ __launch_bounds__(256)
void gemmS(const u16* __restrict__ Ah, const u16* __restrict__ Al, int K,
           const u16* __restrict__ BTh, const u16* __restrict__ BTl,
           const float* __restrict__ bias,
           float* __restrict__ out0, float* __restrict__ out1,
           u16* __restrict__ oh, u16* __restrict__ ol)
{
    __shared__ u16 sm[4][128 * 32];   // Ah, Al, Bh, Bl tiles: 8KB each

    const int tid  = threadIdx.x;
    const int lane = tid & 63;
    const int wv   = tid >> 6;
    const int wr   = wv >> 1;          // 0..1
    const int wc   = wv & 1;           // 0..1
    const int lc   = lane & 15;
    const int kc   = lane >> 4;        // 0..3 (k-chunk of 8)

    const int i    = blockIdx.x;
    const int xcd  = i & 7;
    const int j    = i >> 3;
    const int row0 = (xcd * 32 + j / CT) * 128;
    const int col0 = (j % CT) * 128;

    const u16* Agh = Ah + (size_t)row0 * K;
    const u16* Agl = Al + (size_t)row0 * K;
    const u16* Bgh = BTh + (size_t)col0 * K;
    const u16* Bgl = BTl + (size_t)col0 * K;

    f32x4 acc[4][4];
    #pragma unroll
    for (int m = 0; m < 4; ++m)
        #pragma unroll
        for (int n = 0; n < 4; ++n) acc[m][n] = (f32x4)0.f;

    for (int k0 = 0; k0 < K; k0 += 32) {
        #pragma unroll
        for (int c = 0; c < 2; ++c) {
            int e = c * 256 + tid;
            int row = e >> 2, ch = e & 3;
            int chs = ch ^ ((row >> 1) & 3);
            size_t go = (size_t)row * K + k0 + chs * 8;
            gload16(Agh + go, &sm[0][e * 8]);
            gload16(Agl + go, &sm[1][e * 8]);
            gload16(Bgh + go, &sm[2][e * 8]);
            gload16(Bgl + go, &sm[3][e * 8]);
        }
        __syncthreads();

        short8 ah[4], al[4], bh[4], bl[4];
        #pragma unroll
        for (int m = 0; m < 4; ++m) {
            int row = wr * 64 + m * 16 + lc;
            int off = row * 32 + ((kc ^ ((row >> 1) & 3)) << 3);
            ah[m] = *(const short8*)&sm[0][off];
            al[m] = *(const short8*)&sm[1][off];
        }
        #pragma unroll
        for (int n = 0; n < 4; ++n) {
            int row = wc * 64 + n * 16 + lc;
            int off = row * 32 + ((kc ^ ((row >> 1) & 3)) << 3);
            bh[n] = *(const short8*)&sm[2][off];
            bl[n] = *(const short8*)&sm[3][off];
        }
        #pragma unroll
        for (int m = 0; m < 4; ++m)
            #pragma unroll
            for (int n = 0; n < 4; ++n) {
                acc[m][n] = __builtin_amdgcn_mfma_f32_16x16x32_bf16(ah[m], bh[n], acc[m][n], 0, 0, 0);
                acc[m][n] = __builtin_amdgcn_mfma_f32_16x16x32_bf16(ah[m], bl[n], acc[m][n], 0, 0, 0);
                acc[m][n] = __builtin_amdgcn_mfma_f32_16x16x32_bf16(al[m], bh[n], acc[m][n], 0, 0, 0);
            }
        __syncthreads();
    }

    #pragma unroll
    for (int n = 0; n < 4; ++n) {
        int colg = col0 + wc * 64 + n * 16 + lc;
        float bv = bias[colg];
        #pragma unroll
        for (int m = 0; m < 4; ++m) {
            f32x4 a = acc[m][n];
            #pragma unroll
            for (int r = 0; r < 4; ++r) {
                int rowg = row0 + wr * 64 + m * 16 + kc * 4 + r;
                float v = a[r] + bv;
                if (MODE == 0) {
                    if (colg < 512) {
                        v = siluf_(v);                                   // x_conv
                        u16 hh = f2bf(v);
                        oh[(size_t)rowg * 512 + colg] = hh;
                        ol[(size_t)rowg * 512 + colg] = f2bf(v - bf2f(hh));
                    } else {
                        out0[(size_t)rowg * 512 + colg - 512] = v;       // gate f32
                    }
                } else if (MODE == 2) {
                    if (colg < 512) {
                        out0[(size_t)rowg * 512 + colg] = softplusf_(v);   // DT
                    } else if (colg < 544) {
                        out1[(size_t)rowg * 32 + colg - 512] = v;          // BC
                    }
                } else if (MODE == 4) {
                    out0[(size_t)rowg * 256 + colg] = v;             // y f32
                    u16 hh = f2bf(v);
                    oh[(size_t)rowg * 256 + colg] = hh;              // y planes
                    ol[(size_t)rowg * 256 + colg] = f2bf(v - bf2f(hh));
                } else {  // MODE 5: head layer-1, gelu
                    out0[(size_t)rowg * 128 + colg] = geluf_(v);
                }
            }
        }
    }
}

// ---------------------------------------------------------------------------
// Conversion / prep kernels
// ---------------------------------------------------------------------------
__global__ __launch_bounds__(256)
void split_kernel(const float* __restrict__ s, u16* __restrict__ h,
                  u16* __restrict__ l, int n)
{
    int i = blockIdx.x * 256 + threadIdx.x;
    if (i >= n) return;
    float v = s[i];
    u16 hh = f2bf(v);
    h[i] = hh;
    l[i] = f2bf(v - bf2f(hh));
}

// Weight transposes/splits (gate half of in_proj; dt|bc; out; cat1|e8a) + biases.
// Rows 0-511 of wiT (fused W') are written later by wprod_kernel.
__global__ __launch_bounds__(256)
void prep_weights(const float* __restrict__ in_proj_w,
                  const float* __restrict__ dt_w, const float* __restrict__ bc_w,
                  const float* __restrict__ out_w,
                  const float* __restrict__ cat1_w, const float* __restrict__ e8a_w,
                  const float* __restrict__ dt_b, const float* __restrict__ bc_b,
                  const float* __restrict__ cat1_b, const float* __restrict__ e8a_b,
                  u16* __restrict__ wiTh, u16* __restrict__ wiTl,
                  u16* __restrict__ wdbTh, u16* __restrict__ wdbTl,
                  u16* __restrict__ woTh, u16* __restrict__ woTl,
                  u16* __restrict__ whTh, u16* __restrict__ whTl,
                  float* __restrict__ dbbias, float* __restrict__ hbias)
{
    int idx = blockIdx.x * 256 + threadIdx.x;
    float v; u16 *dh, *dl; int off;
    if (idx < 131072) {                       // in_projT GATE half: rows 512-1023
        int e = idx, n = 512 + (e >> 8), k = e & 255;
        v = in_proj_w[(size_t)k * 1024 + n]; dh = wiTh; dl = wiTl; off = n * 256 + k;
    } else if (idx < 458752) {                // dt|bc T [640][512]
        int e = idx - 131072, n = e >> 9, k = e & 511;
        v = (n < 512) ? dt_w[(size_t)k * 512 + n]
                      : ((n < 544) ? bc_w[(size_t)k * 32 + (n - 512)] : 0.f);
        dh = wdbTh; dl = wdbTl; off = e;
    } else if (idx < 589824) {                // outT [256][512]
        int e = idx - 458752, n = e >> 9, k = e & 511;
        v = out_w[(size_t)k * 256 + n]; dh = woTh; dl = woTl; off = e;
    } else if (idx < 622592) {                // headT [128][256]
        int e = idx - 589824, n = e >> 8, k = e & 255;
        v = (n < 64) ? cat1_w[(size_t)k * 64 + n] : e8a_w[(size_t)k * 64 + (n - 64)];
        dh = whTh; dl = whTl; off = e;
    } else if (idx < 622592 + 640) {
        int i = idx - 622592;
        dbbias[i] = (i < 512) ? dt_b[i] : ((i < 544) ? bc_b[i - 512] : 0.f);
        return;
    } else if (idx < 622592 + 640 + 128) {
        int i = idx - 622592 - 640;
        hbias[i] = (i < 64) ? cat1_b[i] : e8a_b[i - 64];
        return;
    } else return;
    u16 hh = f2bf(v); dh[off] = hh; dl[off] = f2bf(v - bf2f(hh));
}

// W' = Wi_main[256,512] @ conv_w[512,512] -> transposed split planes into
// wiT rows 0-511 ([n][k], k contiguous). f32 compute, 64x64 tiles, BK=16.
__global__ __launch_bounds__(256)
void wprod_kernel(const float* __restrict__ in_proj_w, const float* __restrict__ conv_w,
                  u16* __restrict__ wiTh, u16* __restrict__ wiTl)
{
    __shared__ float As[16][64];       // [j][m], m = k-dim of W'
    __shared__ float Bs[16][65];       // [j][n]
    const int tid = threadIdx.x;
    const int tx = tid & 15, ty = tid >> 4;
    const int m0 = blockIdx.y * 64;    // 0..255
    const int n0 = blockIdx.x * 64;    // 0..511
    float acc[4][4] = {};
    for (int j0 = 0; j0 < 512; j0 += 16) {
        #pragma unroll
        for (int i = 0; i < 4; ++i) {
            int e = tid + i * 256;
            int m = e >> 4, jj = e & 15;
            As[jj][m] = in_proj_w[(size_t)(m0 + m) * 1024 + j0 + jj];
            int n = e & 63, j2 = e >> 6;
            Bs[j2][n] = conv_w[(size_t)(j0 + j2) * 512 + n0 + n];
        }
        __syncthreads();
        #pragma unroll
        for (int jj = 0; jj < 16; ++jj) {
            float av[4], bv[4];
            #pragma unroll
            for (int i = 0; i < 4; ++i) av[i] = As[jj][ty * 4 + i];
            #pragma unroll
            for (int l = 0; l < 4; ++l) bv[l] = Bs[jj][tx * 4 + l];
            #pragma unroll
            for (int i = 0; i < 4; ++i)
                #pragma unroll
                for (int l = 0; l < 4; ++l)
                    acc[i][l] = fmaf(av[i], bv[l], acc[i][l]);
        }
        __syncthreads();
    }
    #pragma unroll
    for (int i = 0; i < 4; ++i) {
        int k = m0 + ty * 4 + i;
        #pragma unroll
        for (int l = 0; l < 4; ++l) {
            int n = n0 + tx * 4 + l;
            float v = acc[i][l];
            u16 hh = f2bf(v);
            wiTh[(size_t)n * 256 + k] = hh;
            wiTl[(size_t)n * 256 + k] = f2bf(v - bf2f(hh));
        }
    }
}

// fused bias: fbias[0..511] = bi_main @ conv_w + conv_b; fbias[512..1023] = bi_gate
__global__ __launch_bounds__(256)
void wbias_kernel(const float* __restrict__ in_proj_b, const float* __restrict__ conv_w,
                  const float* __restrict__ conv_b, float* __restrict__ fbias)
{
    int n = blockIdx.x * 256 + threadIdx.x;
    if (n >= 1024) return;
    if (n < 512) {
        float s = conv_b[n];
        for (int j = 0; j < 512; ++j)
            s = fmaf(in_proj_b[j], conv_w[(size_t)j * 512 + n], s);
        fbias[n] = s;
    } else {
        fbias[n] = in_proj_b[n];
    }
}

// ---------------------------------------------------------------------------
// Selective scan, register-state design. Full batch: grid 1024 blocks.
// ---------------------------------------------------------------------------
__global__ __launch_bounds__(256)
void scan_pass1(const float* __restrict__ DT, const u16* __restrict__ XCh,
                const u16* __restrict__ XCl, const float* __restrict__ BC,
                const float* __restrict__ A_log,
                float* __restrict__ Pbuf, float* __restrict__ Hbuf)
{
    const int bid  = blockIdx.x;
    const int half = bid & 1;
    const int c    = (bid >> 1) & (SCAN_NC - 1);
    const int b    = bid >> 7;
    const int ch   = half * 256 + threadIdx.x;
    const int row0 = b * TT + c * SCAN_L;

    float A[16];
    {
        const float4* ar = (const float4*)(A_log + ch * 16);
        #pragma unroll
        for (int q = 0; q < 4; ++q) {
            float4 v = ar[q];
            A[q * 4 + 0] = -__expf(v.x);
            A[q * 4 + 1] = -__expf(v.y);
            A[q * 4 + 2] = -__expf(v.z);
            A[q * 4 + 3] = -__expf(v.w);
        }
    }

    float h[16];
    #pragma unroll
    for (int s = 0; s < 16; ++s) h[s] = 0.f;
    float dtsum = 0.f;

    const float* dtp = DT  + (size_t)row0 * 512 + ch;
    const u16*   xhp = XCh + (size_t)row0 * 512 + ch;
    const u16*   xlp = XCl + (size_t)row0 * 512 + ch;
    const float* bcp = BC  + (size_t)row0 * 32;

    float dv = dtp[0];
    float xv = bf2f(xhp[0]) + bf2f(xlp[0]);
    for (int t = 0; t < SCAN_L; ++t) {
        const int tn = (t + 1 < SCAN_L) ? t + 1 : t;
        float dvn = dtp[(size_t)tn * 512];
        float xvn = bf2f(xhp[(size_t)tn * 512]) + bf2f(xlp[(size_t)tn * 512]);
        const float* br = bcp + (size_t)t * 32;   // wave-uniform row
        float dtx = dv * xv;
        dtsum += dv;
        #pragma unroll
        for (int s = 0; s < 16; ++s) {
            float a = __expf(dv * A[s]);
            h[s] = fmaf(a, h[s], dtx * br[s]);
        }
        dv = dvn; xv = xvn;
    }

    size_t o = ((size_t)(b * SCAN_NC + c) * 512 + ch) * 16;
    #pragma unroll
    for (int s = 0; s < 16; ++s) {
        Pbuf[o + s] = __expf(dtsum * A[s]);
        Hbuf[o + s] = h[s];
    }
}

__global__ __launch_bounds__(256)
void scan_pass2(const float* __restrict__ Pbuf, float* __restrict__ Hbuf)
{
    const int idx = blockIdx.x * 256 + threadIdx.x;   // 65536 threads
    const int b = idx >> 13;
    const int ds = idx & 8191;
    float hin = 0.f;
    for (int c = 0; c < SCAN_NC; ++c) {
        size_t o = ((size_t)(b * SCAN_NC + c)) * (INNER * SS) + ds;
        float p = Pbuf[o], hh = Hbuf[o];
        Hbuf[o] = hin;
        hin = fmaf(p, hin, hh);
    }
}

// pass3 writes YG planes IN PLACE over XC planes (same thread column,
// read[t+1]-before-write[t]; tail read is dead).
__global__ __launch_bounds__(256)
void scan_pass3(const float* __restrict__ DT, const u16* __restrict__ XCh,
                const u16* __restrict__ XCl, const float* __restrict__ BC,
                const float* __restrict__ A_log, const float* __restrict__ GATE,
                const float* __restrict__ Hin,
                u16* __restrict__ YGh, u16* __restrict__ YGl)
{
    const int bid  = blockIdx.x;
    const int half = bid & 1;
    const int c    = (bid >> 1) & (SCAN_NC - 1);
    const int b    = bid >> 7;
    const int ch   = half * 256 + threadIdx.x;
    const int row0 = b * TT + c * SCAN_L;

    float A[16];
    {
        const float4* ar = (const float4*)(A_log + ch * 16);
        #pragma unroll
        for (int q = 0; q < 4; ++q) {
            float4 v = ar[q];
            A[q * 4 + 0] = -__expf(v.x);
            A[q * 4 + 1] = -__expf(v.y);
            A[q * 4 + 2] = -__expf(v.z);
            A[q * 4 + 3] = -__expf(v.w);
        }
    }

    float h[16];
    {
        size_t o = ((size_t)(b * SCAN_NC + c) * 512 + ch) * 16;
        const float4* hr = (const float4*)(Hin + o);
        #pragma unroll
        for (int q = 0; q < 4; ++q) {
            float4 v = hr[q];
            h[q * 4 + 0] = v.x; h[q * 4 + 1] = v.y;
            h[q * 4 + 2] = v.z; h[q * 4 + 3] = v.w;
        }
    }

    const float* dtp = DT   + (size_t)row0 * 512 + ch;
    const u16*   xhp = XCh  + (size_t)row0 * 512 + ch;
    const u16*   xlp = XCl  + (size_t)row0 * 512 + ch;
    const float* gtp = GATE + (size_t)row0 * 512 + ch;
    const float* bcp = BC   + (size_t)row0 * 32;
    u16* yhp = YGh + (size_t)row0 * 512 + ch;
    u16* ylp = YGl + (size_t)row0 * 512 + ch;

    float dv = dtp[0];
    float xv = bf2f(xhp[0]) + bf2f(xlp[0]);
    float gv = gtp[0];
    for (int t = 0; t < SCAN_L; ++t) {
        const int tn = (t + 1 < SCAN_L) ? t + 1 : t;
        float dvn = dtp[(size_t)tn * 512];
        float xvn = bf2f(xhp[(size_t)tn * 512]) + bf2f(xlp[(size_t)tn * 512]);
        float gvn = gtp[(size_t)tn * 512];
        const float* br = bcp + (size_t)t * 32;   // B=[0..15], C=[16..31]
        float dtx = dv * xv;
        float y = 0.f;
        #pragma unroll
        for (int s = 0; s < 16; ++s) {
            float a = __expf(dv * A[s]);
            h[s] = fmaf(a, h[s], dtx * br[s]);
            y = fmaf(h[s], br[16 + s], y);
        }
        float yg = y * siluf_(gv);
        u16 hh = f2bf(yg);
        yhp[(size_t)t * 512] = hh;
        ylp[(size_t)t * 512] = f2bf(yg - bf2f(hh));
        dv = dvn; xv = xvn; gv = gvn;
    }
}

// ---------------------------------------------------------------------------
// Head finisher (unchanged)
// ---------------------------------------------------------------------------
__global__ __launch_bounds__(256)
void head_finish(const float* __restrict__ F1,
                 const float* __restrict__ w2, const float* __restrict__ b2,
                 const float* __restrict__ w3, const float* __restrict__ b3,
                 const float* __restrict__ wb, const float* __restrict__ bb,
                 const float* __restrict__ cb,
                 float* __restrict__ risk, float* __restrict__ codes_out,
                 float* __restrict__ idx_out)
{
    __shared__ float F1s[64][129];
    __shared__ float w2S[64 * 32];
    __shared__ float wbS[64 * 8];
    __shared__ float cbS[NCODE * 8];
    __shared__ float cnS[NCODE];
    __shared__ float w3S[32];
    __shared__ float b2S[32];
    __shared__ float bbS[8];
    const int tid = threadIdx.x;
    const int tok0 = blockIdx.x * 64;

    for (int e = tid; e < 64 * 128; e += 256)
        F1s[e >> 7][e & 127] = F1[(size_t)tok0 * 128 + e];
    for (int e = tid; e < 64 * 32; e += 256) w2S[e] = w2[e];
    for (int e = tid; e < 64 * 8; e += 256) wbS[e] = wb[e];
    for (int e = tid; e < NCODE * 8; e += 256) cbS[e] = cb[e];
    if (tid < 32) { w3S[tid] = w3[tid]; b2S[tid] = b2[tid]; }
    if (tid < 8) bbS[tid] = bb[tid];
    __syncthreads();
    for (int e = tid; e < NCODE; e += 256) {
        float s = 0.f;
        #pragma unroll
        for (int q = 0; q < 8; ++q) s = fmaf(cbS[e * 8 + q], cbS[e * 8 + q], s);
        cnS[e] = s;
    }
    __syncthreads();

    const int lane = tid & 63;
    const int wv   = tid >> 6;
    const int tl   = wv * 16 + (lane >> 2);
    const int role = lane & 3;
    const float* f1c = &F1s[tl][0];
    const float* f1e = &F1s[tl][64];

    float v = 0.f;
    float bd = 3.4e38f;
    int bi = 0;

    if (role < 2) {
        float f2[16];
        #pragma unroll
        for (int d = 0; d < 16; ++d) f2[d] = b2S[role * 16 + d];
        for (int k = 0; k < 64; ++k) {
            float fv = f1c[k];
            #pragma unroll
            for (int d = 0; d < 16; ++d)
                f2[d] = fmaf(fv, w2S[k * 32 + role * 16 + d], f2[d]);
        }
        #pragma unroll
        for (int d = 0; d < 16; ++d) v = fmaf(f2[d], w3S[role * 16 + d], v);
    } else {
        float ec[8];
        #pragma unroll
        for (int q = 0; q < 8; ++q) ec[q] = bbS[q];
        for (int k = 0; k < 64; ++k) {
            float fv = f1e[k];
            #pragma unroll
            for (int q = 0; q < 8; ++q) ec[q] = fmaf(fv, wbS[k * 8 + q], ec[q]);
        }
        float fn = 0.f;
        #pragma unroll
        for (int q = 0; q < 8; ++q) fn = fmaf(ec[q], ec[q], fn);
        const int base = (role - 2) * 120;
        for (int i = 0; i < 120; ++i) {
            int cc = base + i;
            float dot = 0.f;
            #pragma unroll
            for (int q = 0; q < 8; ++q) dot = fmaf(ec[q], cbS[cc * 8 + q], dot);
            float d = fn + cnS[cc] - 2.f * dot;
            if (d < bd) { bd = d; bi = cc; }
        }
    }

    float vp = __shfl_xor(v, 1, 64);
    float od = __shfl_xor(bd, 1, 64);
    int   oi = __shfl_xor(bi, 1, 64);
    const int tok = tok0 + tl;
    if (role == 0) risk[tok] = sigmoidf_(v + vp + b3[0]);
    if (role == 2) {
        if (od < bd || (od == bd && oi < bi)) { bd = od; bi = oi; }
        idx_out[tok] = (float)bi;
        #pragma unroll
        for (int q = 0; q < 8; ++q)
            codes_out[(size_t)tok * 8 + q] = cbS[bi * 8 + q];
    }
}

// ---------------------------------------------------------------------------
__global__ __launch_bounds__(256)
void vn_kernel(const float* __restrict__ y, float* __restrict__ vn)
{
    const int tid = threadIdx.x;
    const int w = tid >> 6, j = tid & 63;
    const int t = blockIdx.x * 4 + w;
    const int tt = t & (TT - 1);
    const float4* cur = (const float4*)(y + (size_t)t * 256);
    const float4* prv = (const float4*)(y + (size_t)(tt == 0 ? t : t - 1) * 256);
    float4 a = cur[j], b = prv[j];
    float dx = a.x - b.x, dy = a.y - b.y, dz = a.z - b.z, dw = a.w - b.w;
    float ss = dx * dx + dy * dy + dz * dz + dw * dw;
    ss += __shfl_xor(ss, 1, 64);
    ss += __shfl_xor(ss, 2, 64);
    ss += __shfl_xor(ss, 4, 64);
    ss += __shfl_xor(ss, 8, 64);
    ss += __shfl_xor(ss, 16, 64);
    ss += __shfl_xor(ss, 32, 64);
    if (j == 0) vn[t] = sqrtf(ss);
}

__global__ __launch_bounds__(256)
void combined_kernel(const float* __restrict__ risk, const float* __restrict__ vn,
                     float* __restrict__ bif)
{
    const int t = blockIdx.x * 256 + threadIdx.x;
    const int tt = t & (TT - 1);
    float v = vn[t];
    float a = (tt == 0) ? 0.f : fabsf(v - vn[t - 1]);
    float cmb = 0.5f * risk[t] + 0.3f * sigmoidf_(v) + 0.2f * sigmoidf_(a);
    bif[t] = (cmb > 0.7f) ? 1.f : 0.f;
}

// ---------------------------------------------------------------------------
extern "C" void kernel_launch(void* const* d_in, const int* in_sizes, int n_in,
                              void* d_out, int out_size, void* d_ws, size_t ws_size,
                              hipStream_t stream)
{
    const float* x          = (const float*)d_in[0];
    const float* in_proj_w  = (const float*)d_in[1];
    const float* in_proj_b  = (const float*)d_in[2];
    const float* conv_w     = (const float*)d_in[3];
    const float* conv_b     = (const float*)d_in[4];
    const float* A_log      = (const float*)d_in[5];
    const float* bc_w       = (const float*)d_in[6];
    const float* bc_b       = (const float*)d_in[7];
    const float* dt_w       = (const float*)d_in[8];
    const float* dt_b       = (const float*)d_in[9];
    const float* out_w      = (const float*)d_in[10];
    const float* out_b      = (const float*)d_in[11];
    const float* cat1_w     = (const float*)d_in[12];
    const float* cat1_b     = (const float*)d_in[13];
    const float* cat2_w     = (const float*)d_in[14];
    const float* cat2_b     = (const float*)d_in[15];
    const float* risk_w     = (const float*)d_in[16];
    const float* risk_b     = (const float*)d_in[17];
    const float* e8a_w      = (const float*)d_in[18];
    const float* e8a_b      = (const float*)d_in[19];
    const float* e8b_w      = (const float*)d_in[20];
    const float* e8b_b      = (const float*)d_in[21];
    const float* codebook   = (const float*)d_in[22];

    float* out = (float*)d_out;
    float* y_out     = out;                        // [B,T,256]
    float* codes_out = out + (size_t)MTOK * 256;   // [B,T,8]
    float* idx_out   = codes_out + (size_t)MTOK * 8;
    float* bif_out   = idx_out + MTOK;

    // ---- workspace layout (G=1, heavy aliasing) ----
    const size_t AL = 255;
    #define ALN(x) (((x) + AL) & ~AL)
    char* p = (char*)d_ws;
    #define TAKE(T, name, bytes) T* name = (T*)p; p += ALN((size_t)(bytes));
    TAKE(float, risk, MTOK * 4)
    TAKE(float, vn,   MTOK * 4)
    TAKE(u16, wiTh, (size_t)1024 * 256 * 2)   // rows 0-511: fused W'; 512-1023: gate
    TAKE(u16, wiTl, (size_t)1024 * 256 * 2)
    TAKE(u16, wdbTh, (size_t)640 * 512 * 2)
    TAKE(u16, wdbTl, (size_t)640 * 512 * 2)
    TAKE(u16, woTh, (size_t)256 * 512 * 2)
    TAKE(u16, woTl, (size_t)256 * 512 * 2)
    TAKE(u16, whTh, (size_t)128 * 256 * 2)
    TAKE(u16, whTl, (size_t)128 * 256 * 2)
    TAKE(float, dbbias, 640 * 4)
    TAKE(float, hbias, 128 * 4)
    TAKE(float, fbias, 1024 * 4)
    TAKE(u16, A0, (size_t)2 * MTOK * 512 * 2)   // region A: 64 MiB (XC/YG planes)
    TAKE(u16, B0, (size_t)2 * MTOK * 512 * 2)   // region B: 64 MiB (x -> DT -> y planes)
    TAKE(float, GATE, (size_t)MTOK * 512 * 4)   // 64 MiB (-> F1)
    TAKE(float, BC, (size_t)MTOK * 32 * 4)      // 4 MiB

    // region A: XC planes; pass3 overwrites in place with YG planes
    u16* XCh = A0;
    u16* XCl = A0 + (size_t)MTOK * 512;
    // region B: x planes -> DT f32 -> y planes
    u16* xh  = B0;
    u16* xl  = B0 + (size_t)MTOK * 512;
    float* DT = (float*)B0;
    u16* yh   = B0;
    u16* yl   = B0 + (size_t)MTOK * 512;
    // GATE -> F1
    float* F1 = GATE;
    // P/H live in d_out's y slab (2 x 16.78MB), overwritten by out_proj
    float* Pb = y_out;
    float* Hb = y_out + (size_t)MTOK * 128;

    // ---- prep ----
    split_kernel<<<(MTOK * 256 + 255) / 256, 256, 0, stream>>>(x, xh, xl, MTOK * 256);
    prep_weights<<<(623360 + 255) / 256, 256, 0, stream>>>(
        in_proj_w, dt_w, bc_w, out_w, cat1_w, e8a_w,
        dt_b, bc_b, cat1_b, e8a_b,
        wiTh, wiTl, wdbTh, wdbTl, woTh, woTl, whTh, whTl,
        dbbias, hbias);
    wprod_kernel<<<dim3(8, 4), 256, 0, stream>>>(in_proj_w, conv_w, wiTh, wiTl);
    wbias_kernel<<<4, 256, 0, stream>>>(in_proj_b, conv_w, conv_b, fbias);

    // ---- pipeline, full batch (grid = 256 * CT, XCD-aware mapping) ----
    // 1. fused in_proj+conv: cols<512 silu -> XC planes; cols>=512 -> GATE f32
    gemmS<0, 8><<<256 * 8, 256, 0, stream>>>(
        xh, xl, 256, wiTh, wiTl, fbias, GATE, nullptr, XCh, XCl);
    // 2. dt+bc fused: softplus -> DT f32 (region B, over x planes), raw -> BC
    gemmS<2, 5><<<256 * 5, 256, 0, stream>>>(
        XCh, XCl, 512, wdbTh, wdbTl, dbbias, DT, BC, nullptr, nullptr);
    // 3-5. chunked scan; P/H in d_out y slab; YG in place over XC
    scan_pass1<<<BB * SCAN_NC * 2, 256, 0, stream>>>(DT, XCh, XCl, BC, A_log, Pb, Hb);
    scan_pass2<<<256, 256, 0, stream>>>(Pb, Hb);
    scan_pass3<<<BB * SCAN_NC * 2, 256, 0, stream>>>(DT, XCh, XCl, BC, A_log, GATE,
                                                     Hb, XCh, XCl);
    // 6. out_proj -> y f32 (over P/H) + y planes (region B, over DT)
    gemmS<4, 2><<<256 * 2, 256, 0, stream>>>(
        XCh, XCl, 512, woTh, woTl, out_b, y_out, nullptr, yh, yl);
    // 7. head layer-1 -> F1 (over GATE)
    gemmS<5, 1><<<256 * 1, 256, 0, stream>>>(
        yh, yl, 256, whTh, whTl, hbias, F1, nullptr, nullptr, nullptr);
    // 8. finishers
    head_finish<<<MTOK / 64, 256, 0, stream>>>(F1, cat2_w, cat2_b, risk_w, risk_b,
                                               e8b_w, e8b_b, codebook,
                                               risk, codes_out, idx_out);
    vn_kernel<<<MTOK / 4, 256, 0, stream>>>(y_out, vn);
    combined_kernel<<<MTOK / 256, 256, 0, stream>>>(risk, vn, bif_out);
}

// Round 9
// 689.652 us; speedup vs baseline: 1.2911x; 1.2911x over previous
//
#include <hip/hip_runtime.h>
#include <hip/hip_bf16.h>
#include <math.h>

// Problem dims
#define BB 8
#define TT 4096
#define DD 256
#define INNER 512
#define SS 16
#define MTOK (BB*TT)          // 32768 tokens
#define NCODE 240

#define SCAN_NC 64
#define SCAN_L  64            // TT / SCAN_NC

typedef unsigned short u16;
typedef unsigned int   u32;
typedef __attribute__((ext_vector_type(8))) short short8;   // 8 bf16 (4 VGPRs)
typedef __attribute__((ext_vector_type(4))) float f32x4;    // 4 fp32 acc

__device__ __forceinline__ float sigmoidf_(float x) { return 1.f / (1.f + expf(-x)); }
__device__ __forceinline__ float siluf_(float x)    { return x / (1.f + expf(-x)); }
__device__ __forceinline__ float geluf_(float x) {
    float x3 = x * x * x;
    return 0.5f * x * (1.f + tanhf(0.7978845608028654f * (x + 0.044715f * x3)));
}
__device__ __forceinline__ float softplusf_(float x) {
    return fmaxf(x, 0.f) + log1pf(expf(-fabsf(x)));
}

// bf16 round-to-nearest-even helpers
__device__ __forceinline__ u16 f2bf(float v) {
    u32 u = __float_as_uint(v);
    u32 r = (u + 0x7FFFu + ((u >> 16) & 1u)) >> 16;
    return (u16)r;
}
__device__ __forceinline__ float bf2f(u16 h) {
    return __uint_as_float(((u32)h) << 16);
}

__device__ __forceinline__ void gload16(const void* g, void* l) {
    __builtin_amdgcn_global_load_lds((const __attribute__((address_space(1))) u32*)g,
                                     (__attribute__((address_space(3))) u32*)l, 16, 0, 0);
}

// ---------------------------------------------------------------------------
// Split-bf16 MFMA GEMM, 128x128 tile (4 waves, 64x64/wave).
// MODE: 0=in_proj (cols<512 -> MAIN planes, cols>=512 -> GATE f32)
//       1=conv   (silu -> XC planes)
//       2=dt+bc  (cols<512 softplus -> DT f32; cols 512..543 -> BC f32)
// CT = N/128. XCD-aware (T1): xcd=i&7 owns 32 row-tiles; col fastest within XCD.
// ---------------------------------------------------------------------------
template<int MODE, int CT>
__global__ __launch_bounds__(256)
void gemmS(const u16* __restrict__ Ah, const u16* __restrict__ Al, int K,
           const u16* __restrict__ BTh, const u16* __restrict__ BTl,
           const float* __restrict__ bias,
           float* __restrict__ out0, float* __restrict__ out1,
           u16* __restrict__ oh, u16* __restrict__ ol)
{
    __shared__ u16 sm[4][128 * 32];   // Ah, Al, Bh, Bl tiles: 8KB each

    const int tid  = threadIdx.x;
    const int lane = tid & 63;
    const int wv   = tid >> 6;
    const int wr   = wv >> 1;          // 0..1
    const int wc   = wv & 1;           // 0..1
    const int lc   = lane & 15;
    const int kc   = lane >> 4;        // 0..3 (k-chunk of 8)

    const int i    = blockIdx.x;
    const int xcd  = i & 7;
    const int j    = i >> 3;
    const int row0 = (xcd * 32 + j / CT) * 128;
    const int col0 = (j % CT) * 128;

    const u16* Agh = Ah + (size_t)row0 * K;
    const u16* Agl = Al + (size_t)row0 * K;
    const u16* Bgh = BTh + (size_t)col0 * K;
    const u16* Bgl = BTl + (size_t)col0 * K;

    f32x4 acc[4][4];
    #pragma unroll
    for (int m = 0; m < 4; ++m)
        #pragma unroll
        for (int n = 0; n < 4; ++n) acc[m][n] = (f32x4)0.f;

    for (int k0 = 0; k0 < K; k0 += 32) {
        #pragma unroll
        for (int c = 0; c < 2; ++c) {
            int e = c * 256 + tid;
            int row = e >> 2, ch = e & 3;
            int chs = ch ^ ((row >> 1) & 3);
            size_t go = (size_t)row * K + k0 + chs * 8;
            gload16(Agh + go, &sm[0][e * 8]);
            gload16(Agl + go, &sm[1][e * 8]);
            gload16(Bgh + go, &sm[2][e * 8]);
            gload16(Bgl + go, &sm[3][e * 8]);
        }
        __syncthreads();

        short8 ah[4], al[4], bh[4], bl[4];
        #pragma unroll
        for (int m = 0; m < 4; ++m) {
            int row = wr * 64 + m * 16 + lc;
            int off = row * 32 + ((kc ^ ((row >> 1) & 3)) << 3);
            ah[m] = *(const short8*)&sm[0][off];
            al[m] = *(const short8*)&sm[1][off];
        }
        #pragma unroll
        for (int n = 0; n < 4; ++n) {
            int row = wc * 64 + n * 16 + lc;
            int off = row * 32 + ((kc ^ ((row >> 1) & 3)) << 3);
            bh[n] = *(const short8*)&sm[2][off];
            bl[n] = *(const short8*)&sm[3][off];
        }
        #pragma unroll
        for (int m = 0; m < 4; ++m)
            #pragma unroll
            for (int n = 0; n < 4; ++n) {
                acc[m][n] = __builtin_amdgcn_mfma_f32_16x16x32_bf16(ah[m], bh[n], acc[m][n], 0, 0, 0);
                acc[m][n] = __builtin_amdgcn_mfma_f32_16x16x32_bf16(ah[m], bl[n], acc[m][n], 0, 0, 0);
                acc[m][n] = __builtin_amdgcn_mfma_f32_16x16x32_bf16(al[m], bh[n], acc[m][n], 0, 0, 0);
            }
        __syncthreads();
    }

    #pragma unroll
    for (int n = 0; n < 4; ++n) {
        int colg = col0 + wc * 64 + n * 16 + lc;
        float bv = bias[colg];
        #pragma unroll
        for (int m = 0; m < 4; ++m) {
            f32x4 a = acc[m][n];
            #pragma unroll
            for (int r = 0; r < 4; ++r) {
                int rowg = row0 + wr * 64 + m * 16 + kc * 4 + r;
                float v = a[r] + bv;
                if (MODE == 0) {
                    if (colg < 512) {
                        u16 hh = f2bf(v);
                        oh[(size_t)rowg * 512 + colg] = hh;
                        ol[(size_t)rowg * 512 + colg] = f2bf(v - bf2f(hh));
                    } else {
                        out0[(size_t)rowg * 512 + colg - 512] = v;   // gate f32
                    }
                } else if (MODE == 1) {
                    v = siluf_(v);
                    u16 hh = f2bf(v);
                    oh[(size_t)rowg * 512 + colg] = hh;
                    ol[(size_t)rowg * 512 + colg] = f2bf(v - bf2f(hh));
                } else if (MODE == 2) {
                    if (colg < 512) {
                        out0[(size_t)rowg * 512 + colg] = softplusf_(v);   // DT
                    } else if (colg < 544) {
                        out1[(size_t)rowg * 32 + colg - 512] = v;          // BC
                    }
                }
            }
        }
    }
}

// ---------------------------------------------------------------------------
// Split-bf16 MFMA GEMM, 64x128 tile (4 waves, 16 rows x 128 cols per wave).
// Higher grid parallelism for the small-N memory-bound GEMMs.
// MODE: 4=out (y f32 + y planes), 5=head (gelu -> F1 f32 [M,128])
// Grid = (M/64) * CT blocks; xcd owns 64 row-tiles.
// ---------------------------------------------------------------------------
template<int MODE, int CT>
__global__ __launch_bounds__(256)
void gemmS64(const u16* __restrict__ Ah, const u16* __restrict__ Al, int K,
             const u16* __restrict__ BTh, const u16* __restrict__ BTl,
             const float* __restrict__ bias,
             float* __restrict__ out0, u16* __restrict__ oh, u16* __restrict__ ol)
{
    __shared__ u16 smA[2][64 * 32];    // 4KB each
    __shared__ u16 smB[2][128 * 32];   // 8KB each

    const int tid  = threadIdx.x;
    const int lane = tid & 63;
    const int wv   = tid >> 6;         // 0..3: wave's 16-row strip
    const int lc   = lane & 15;
    const int kc   = lane >> 4;        // 0..3

    const int i    = blockIdx.x;
    const int xcd  = i & 7;
    const int j    = i >> 3;
    const int row0 = (xcd * 64 + j / CT) * 64;
    const int col0 = (j % CT) * 128;

    const u16* Agh = Ah + (size_t)row0 * K;
    const u16* Agl = Al + (size_t)row0 * K;
    const u16* Bgh = BTh + (size_t)col0 * K;
    const u16* Bgl = BTl + (size_t)col0 * K;

    f32x4 acc[8];
    #pragma unroll
    for (int n = 0; n < 8; ++n) acc[n] = (f32x4)0.f;

    for (int k0 = 0; k0 < K; k0 += 32) {
        {   // stage A: 64 rows x 4 chunks = 256 vectors, 1 per thread per plane
            int e = tid;
            int row = e >> 2, ch = e & 3;
            int chs = ch ^ ((row >> 1) & 3);
            size_t go = (size_t)row * K + k0 + chs * 8;
            gload16(Agh + go, &smA[0][e * 8]);
            gload16(Agl + go, &smA[1][e * 8]);
        }
        #pragma unroll
        for (int c = 0; c < 2; ++c) {   // stage B: 128 rows x 4 chunks
            int e = c * 256 + tid;
            int row = e >> 2, ch = e & 3;
            int chs = ch ^ ((row >> 1) & 3);
            size_t go = (size_t)row * K + k0 + chs * 8;
            gload16(Bgh + go, &smB[0][e * 8]);
            gload16(Bgl + go, &smB[1][e * 8]);
        }
        __syncthreads();

        short8 ah, al;
        {
            int row = wv * 16 + lc;
            int off = row * 32 + ((kc ^ ((row >> 1) & 3)) << 3);
            ah = *(const short8*)&smA[0][off];
            al = *(const short8*)&smA[1][off];
        }
        #pragma unroll
        for (int n = 0; n < 8; ++n) {
            int row = n * 16 + lc;
            int off = row * 32 + ((kc ^ ((row >> 1) & 3)) << 3);
            short8 bh = *(const short8*)&smB[0][off];
            short8 bl = *(const short8*)&smB[1][off];
            acc[n] = __builtin_amdgcn_mfma_f32_16x16x32_bf16(ah, bh, acc[n], 0, 0, 0);
            acc[n] = __builtin_amdgcn_mfma_f32_16x16x32_bf16(ah, bl, acc[n], 0, 0, 0);
            acc[n] = __builtin_amdgcn_mfma_f32_16x16x32_bf16(al, bh, acc[n], 0, 0, 0);
        }
        __syncthreads();
    }

    #pragma unroll
    for (int n = 0; n < 8; ++n) {
        int colg = col0 + n * 16 + lc;
        float bv = bias[colg];
        f32x4 a = acc[n];
        #pragma unroll
        for (int r = 0; r < 4; ++r) {
            int rowg = row0 + wv * 16 + kc * 4 + r;
            float v = a[r] + bv;
            if (MODE == 4) {
                out0[(size_t)rowg * 256 + colg] = v;             // y f32
                u16 hh = f2bf(v);
                oh[(size_t)rowg * 256 + colg] = hh;              // y planes
                ol[(size_t)rowg * 256 + colg] = f2bf(v - bf2f(hh));
            } else {  // MODE 5: head layer-1, gelu
                out0[(size_t)rowg * 128 + colg] = geluf_(v);
            }
        }
    }
}

// ---------------------------------------------------------------------------
// Conversion / prep kernels
// ---------------------------------------------------------------------------
__global__ __launch_bounds__(256)
void split_kernel(const float* __restrict__ s, u16* __restrict__ h,
                  u16* __restrict__ l, int n)
{
    int i = blockIdx.x * 256 + threadIdx.x;
    if (i >= n) return;
    float v = s[i];
    u16 hh = f2bf(v);
    h[i] = hh;
    l[i] = f2bf(v - bf2f(hh));
}

// All weight transposes/splits + fused dt|bc and cat1|e8a concats, one launch.
__global__ __launch_bounds__(256)
void prep_weights(const float* __restrict__ in_proj_w, const float* __restrict__ conv_w,
                  const float* __restrict__ dt_w, const float* __restrict__ bc_w,
                  const float* __restrict__ out_w,
                  const float* __restrict__ cat1_w, const float* __restrict__ e8a_w,
                  const float* __restrict__ dt_b, const float* __restrict__ bc_b,
                  const float* __restrict__ cat1_b, const float* __restrict__ e8a_b,
                  u16* __restrict__ wiTh, u16* __restrict__ wiTl,
                  u16* __restrict__ wcTh, u16* __restrict__ wcTl,
                  u16* __restrict__ wdbTh, u16* __restrict__ wdbTl,
                  u16* __restrict__ woTh, u16* __restrict__ woTl,
                  u16* __restrict__ whTh, u16* __restrict__ whTl,
                  float* __restrict__ dbbias, float* __restrict__ hbias)
{
    int idx = blockIdx.x * 256 + threadIdx.x;
    float v; u16 *dh, *dl; int off;
    if (idx < 262144) {                       // in_projT [1024][256]
        int e = idx, n = e >> 8, k = e & 255;
        v = in_proj_w[(size_t)k * 1024 + n]; dh = wiTh; dl = wiTl; off = e;
    } else if (idx < 524288) {                // convT [512][512]
        int e = idx - 262144, n = e >> 9, k = e & 511;
        v = conv_w[(size_t)k * 512 + n]; dh = wcTh; dl = wcTl; off = e;
    } else if (idx < 851968) {                // dt|bc T [640][512]
        int e = idx - 524288, n = e >> 9, k = e & 511;
        v = (n < 512) ? dt_w[(size_t)k * 512 + n]
                      : ((n < 544) ? bc_w[(size_t)k * 32 + (n - 512)] : 0.f);
        dh = wdbTh; dl = wdbTl; off = e;
    } else if (idx < 983040) {                // outT [256][512]
        int e = idx - 851968, n = e >> 9, k = e & 511;
        v = out_w[(size_t)k * 256 + n]; dh = woTh; dl = woTl; off = e;
    } else if (idx < 1015808) {               // headT [128][256]
        int e = idx - 983040, n = e >> 8, k = e & 255;
        v = (n < 64) ? cat1_w[(size_t)k * 64 + n] : e8a_w[(size_t)k * 64 + (n - 64)];
        dh = whTh; dl = whTl; off = e;
    } else if (idx < 1015808 + 640) {
        int i = idx - 1015808;
        dbbias[i] = (i < 512) ? dt_b[i] : ((i < 544) ? bc_b[i - 512] : 0.f);
        return;
    } else if (idx < 1015808 + 640 + 128) {
        int i = idx - 1015808 - 640;
        hbias[i] = (i < 64) ? cat1_b[i] : e8a_b[i - 64];
        return;
    } else return;
    u16 hh = f2bf(v); dh[off] = hh; dl[off] = f2bf(v - bf2f(hh));
}

// ---------------------------------------------------------------------------
// Selective scan, register-state design. Full batch: grid 1024 blocks.
// ---------------------------------------------------------------------------
__global__ __launch_bounds__(256)
void scan_pass1(const float* __restrict__ DT, const u16* __restrict__ XCh,
                const u16* __restrict__ XCl, const float* __restrict__ BC,
                const float* __restrict__ A_log,
                float* __restrict__ Pbuf, float* __restrict__ Hbuf)
{
    const int bid  = blockIdx.x;
    const int half = bid & 1;
    const int c    = (bid >> 1) & (SCAN_NC - 1);
    const int b    = bid >> 7;
    const int ch   = half * 256 + threadIdx.x;
    const int row0 = b * TT + c * SCAN_L;

    float A[16];
    {
        const float4* ar = (const float4*)(A_log + ch * 16);
        #pragma unroll
        for (int q = 0; q < 4; ++q) {
            float4 v = ar[q];
            A[q * 4 + 0] = -__expf(v.x);
            A[q * 4 + 1] = -__expf(v.y);
            A[q * 4 + 2] = -__expf(v.z);
            A[q * 4 + 3] = -__expf(v.w);
        }
    }

    float h[16];
    #pragma unroll
    for (int s = 0; s < 16; ++s) h[s] = 0.f;
    float dtsum = 0.f;

    const float* dtp = DT  + (size_t)row0 * 512 + ch;
    const u16*   xhp = XCh + (size_t)row0 * 512 + ch;
    const u16*   xlp = XCl + (size_t)row0 * 512 + ch;
    const float* bcp = BC  + (size_t)row0 * 32;

    float dv = dtp[0];
    float xv = bf2f(xhp[0]) + bf2f(xlp[0]);
    for (int t = 0; t < SCAN_L; ++t) {
        const int tn = (t + 1 < SCAN_L) ? t + 1 : t;
        float dvn = dtp[(size_t)tn * 512];
        float xvn = bf2f(xhp[(size_t)tn * 512]) + bf2f(xlp[(size_t)tn * 512]);
        const float* br = bcp + (size_t)t * 32;   // wave-uniform row
        float dtx = dv * xv;
        dtsum += dv;
        #pragma unroll
        for (int s = 0; s < 16; ++s) {
            float a = __expf(dv * A[s]);
            h[s] = fmaf(a, h[s], dtx * br[s]);
        }
        dv = dvn; xv = xvn;
    }

    size_t o = ((size_t)(b * SCAN_NC + c) * 512 + ch) * 16;
    #pragma unroll
    for (int s = 0; s < 16; ++s) {
        Pbuf[o + s] = __expf(dtsum * A[s]);
        Hbuf[o + s] = h[s];
    }
}

__global__ __launch_bounds__(256)
void scan_pass2(const float* __restrict__ Pbuf, float* __restrict__ Hbuf)
{
    const int idx = blockIdx.x * 256 + threadIdx.x;   // 65536 threads
    const int b = idx >> 13;
    const int ds = idx & 8191;
    float hin = 0.f;
    for (int c = 0; c < SCAN_NC; ++c) {
        size_t o = ((size_t)(b * SCAN_NC + c)) * (INNER * SS) + ds;
        float p = Pbuf[o], hh = Hbuf[o];
        Hbuf[o] = hin;
        hin = fmaf(p, hin, hh);
    }
}

// pass3 writes YG planes IN PLACE over XC planes (same thread column,
// read[t+1]-before-write[t]; tail read is dead).
__global__ __launch_bounds__(256)
void scan_pass3(const float* __restrict__ DT, const u16* __restrict__ XCh,
                const u16* __restrict__ XCl, const float* __restrict__ BC,
                const float* __restrict__ A_log, const float* __restrict__ GATE,
                const float* __restrict__ Hin,
                u16* __restrict__ YGh, u16* __restrict__ YGl)
{
    const int bid  = blockIdx.x;
    const int half = bid & 1;
    const int c    = (bid >> 1) & (SCAN_NC - 1);
    const int b    = bid >> 7;
    const int ch   = half * 256 + threadIdx.x;
    const int row0 = b * TT + c * SCAN_L;

    float A[16];
    {
        const float4* ar = (const float4*)(A_log + ch * 16);
        #pragma unroll
        for (int q = 0; q < 4; ++q) {
            float4 v = ar[q];
            A[q * 4 + 0] = -__expf(v.x);
            A[q * 4 + 1] = -__expf(v.y);
            A[q * 4 + 2] = -__expf(v.z);
            A[q * 4 + 3] = -__expf(v.w);
        }
    }

    float h[16];
    {
        size_t o = ((size_t)(b * SCAN_NC + c) * 512 + ch) * 16;
        const float4* hr = (const float4*)(Hin + o);
        #pragma unroll
        for (int q = 0; q < 4; ++q) {
            float4 v = hr[q];
            h[q * 4 + 0] = v.x; h[q * 4 + 1] = v.y;
            h[q * 4 + 2] = v.z; h[q * 4 + 3] = v.w;
        }
    }

    const float* dtp = DT   + (size_t)row0 * 512 + ch;
    const u16*   xhp = XCh  + (size_t)row0 * 512 + ch;
    const u16*   xlp = XCl  + (size_t)row0 * 512 + ch;
    const float* gtp = GATE + (size_t)row0 * 512 + ch;
    const float* bcp = BC   + (size_t)row0 * 32;
    u16* yhp = YGh + (size_t)row0 * 512 + ch;
    u16* ylp = YGl + (size_t)row0 * 512 + ch;

    float dv = dtp[0];
    float xv = bf2f(xhp[0]) + bf2f(xlp[0]);
    float gv = gtp[0];
    for (int t = 0; t < SCAN_L; ++t) {
        const int tn = (t + 1 < SCAN_L) ? t + 1 : t;
        float dvn = dtp[(size_t)tn * 512];
        float xvn = bf2f(xhp[(size_t)tn * 512]) + bf2f(xlp[(size_t)tn * 512]);
        float gvn = gtp[(size_t)tn * 512];
        const float* br = bcp + (size_t)t * 32;   // B=[0..15], C=[16..31]
        float dtx = dv * xv;
        float y = 0.f;
        #pragma unroll
        for (int s = 0; s < 16; ++s) {
            float a = __expf(dv * A[s]);
            h[s] = fmaf(a, h[s], dtx * br[s]);
            y = fmaf(h[s], br[16 + s], y);
        }
        float yg = y * siluf_(gv);
        u16 hh = f2bf(yg);
        yhp[(size_t)t * 512] = hh;
        ylp[(size_t)t * 512] = f2bf(yg - bf2f(hh));
        dv = dvn; xv = xvn; gv = gvn;
    }
}

// ---------------------------------------------------------------------------
// Head finisher (unchanged)
// ---------------------------------------------------------------------------
__global__ __launch_bounds__(256)
void head_finish(const float* __restrict__ F1,
                 const float* __restrict__ w2, const float* __restrict__ b2,
                 const float* __restrict__ w3, const float* __restrict__ b3,
                 const float* __restrict__ wb, const float* __restrict__ bb,
                 const float* __restrict__ cb,
                 float* __restrict__ risk, float* __restrict__ codes_out,
                 float* __restrict__ idx_out)
{
    __shared__ float F1s[64][129];
    __shared__ float w2S[64 * 32];
    __shared__ float wbS[64 * 8];
    __shared__ float cbS[NCODE * 8];
    __shared__ float cnS[NCODE];
    __shared__ float w3S[32];
    __shared__ float b2S[32];
    __shared__ float bbS[8];
    const int tid = threadIdx.x;
    const int tok0 = blockIdx.x * 64;

    for (int e = tid; e < 64 * 128; e += 256)
        F1s[e >> 7][e & 127] = F1[(size_t)tok0 * 128 + e];
    for (int e = tid; e < 64 * 32; e += 256) w2S[e] = w2[e];
    for (int e = tid; e < 64 * 8; e += 256) wbS[e] = wb[e];
    for (int e = tid; e < NCODE * 8; e += 256) cbS[e] = cb[e];
    if (tid < 32) { w3S[tid] = w3[tid]; b2S[tid] = b2[tid]; }
    if (tid < 8) bbS[tid] = bb[tid];
    __syncthreads();
    for (int e = tid; e < NCODE; e += 256) {
        float s = 0.f;
        #pragma unroll
        for (int q = 0; q < 8; ++q) s = fmaf(cbS[e * 8 + q], cbS[e * 8 + q], s);
        cnS[e] = s;
    }
    __syncthreads();

    const int lane = tid & 63;
    const int wv   = tid >> 6;
    const int tl   = wv * 16 + (lane >> 2);
    const int role = lane & 3;
    const float* f1c = &F1s[tl][0];
    const float* f1e = &F1s[tl][64];

    float v = 0.f;
    float bd = 3.4e38f;
    int bi = 0;

    if (role < 2) {
        float f2[16];
        #pragma unroll
        for (int d = 0; d < 16; ++d) f2[d] = b2S[role * 16 + d];
        for (int k = 0; k < 64; ++k) {
            float fv = f1c[k];
            #pragma unroll
            for (int d = 0; d < 16; ++d)
                f2[d] = fmaf(fv, w2S[k * 32 + role * 16 + d], f2[d]);
        }
        #pragma unroll
        for (int d = 0; d < 16; ++d) v = fmaf(f2[d], w3S[role * 16 + d], v);
    } else {
        float ec[8];
        #pragma unroll
        for (int q = 0; q < 8; ++q) ec[q] = bbS[q];
        for (int k = 0; k < 64; ++k) {
            float fv = f1e[k];
            #pragma unroll
            for (int q = 0; q < 8; ++q) ec[q] = fmaf(fv, wbS[k * 8 + q], ec[q]);
        }
        float fn = 0.f;
        #pragma unroll
        for (int q = 0; q < 8; ++q) fn = fmaf(ec[q], ec[q], fn);
        const int base = (role - 2) * 120;
        for (int i = 0; i < 120; ++i) {
            int cc = base + i;
            float dot = 0.f;
            #pragma unroll
            for (int q = 0; q < 8; ++q) dot = fmaf(ec[q], cbS[cc * 8 + q], dot);
            float d = fn + cnS[cc] - 2.f * dot;
            if (d < bd) { bd = d; bi = cc; }
        }
    }

    float vp = __shfl_xor(v, 1, 64);
    float od = __shfl_xor(bd, 1, 64);
    int   oi = __shfl_xor(bi, 1, 64);
    const int tok = tok0 + tl;
    if (role == 0) risk[tok] = sigmoidf_(v + vp + b3[0]);
    if (role == 2) {
        if (od < bd || (od == bd && oi < bi)) { bd = od; bi = oi; }
        idx_out[tok] = (float)bi;
        #pragma unroll
        for (int q = 0; q < 8; ++q)
            codes_out[(size_t)tok * 8 + q] = cbS[bi * 8 + q];
    }
}

// ---------------------------------------------------------------------------
__global__ __launch_bounds__(256)
void vn_kernel(const float* __restrict__ y, float* __restrict__ vn)
{
    const int tid = threadIdx.x;
    const int w = tid >> 6, j = tid & 63;
    const int t = blockIdx.x * 4 + w;
    const int tt = t & (TT - 1);
    const float4* cur = (const float4*)(y + (size_t)t * 256);
    const float4* prv = (const float4*)(y + (size_t)(tt == 0 ? t : t - 1) * 256);
    float4 a = cur[j], b = prv[j];
    float dx = a.x - b.x, dy = a.y - b.y, dz = a.z - b.z, dw = a.w - b.w;
    float ss = dx * dx + dy * dy + dz * dz + dw * dw;
    ss += __shfl_xor(ss, 1, 64);
    ss += __shfl_xor(ss, 2, 64);
    ss += __shfl_xor(ss, 4, 64);
    ss += __shfl_xor(ss, 8, 64);
    ss += __shfl_xor(ss, 16, 64);
    ss += __shfl_xor(ss, 32, 64);
    if (j == 0) vn[t] = sqrtf(ss);
}

__global__ __launch_bounds__(256)
void combined_kernel(const float* __restrict__ risk, const float* __restrict__ vn,
                     float* __restrict__ bif)
{
    const int t = blockIdx.x * 256 + threadIdx.x;
    const int tt = t & (TT - 1);
    float v = vn[t];
    float a = (tt == 0) ? 0.f : fabsf(v - vn[t - 1]);
    float cmb = 0.5f * risk[t] + 0.3f * sigmoidf_(v) + 0.2f * sigmoidf_(a);
    bif[t] = (cmb > 0.7f) ? 1.f : 0.f;
}

// ---------------------------------------------------------------------------
extern "C" void kernel_launch(void* const* d_in, const int* in_sizes, int n_in,
                              void* d_out, int out_size, void* d_ws, size_t ws_size,
                              hipStream_t stream)
{
    const float* x          = (const float*)d_in[0];
    const float* in_proj_w  = (const float*)d_in[1];
    const float* in_proj_b  = (const float*)d_in[2];
    const float* conv_w     = (const float*)d_in[3];
    const float* conv_b     = (const float*)d_in[4];
    const float* A_log      = (const float*)d_in[5];
    const float* bc_w       = (const float*)d_in[6];
    const float* bc_b       = (const float*)d_in[7];
    const float* dt_w       = (const float*)d_in[8];
    const float* dt_b       = (const float*)d_in[9];
    const float* out_w      = (const float*)d_in[10];
    const float* out_b      = (const float*)d_in[11];
    const float* cat1_w     = (const float*)d_in[12];
    const float* cat1_b     = (const float*)d_in[13];
    const float* cat2_w     = (const float*)d_in[14];
    const float* cat2_b     = (const float*)d_in[15];
    const float* risk_w     = (const float*)d_in[16];
    const float* risk_b     = (const float*)d_in[17];
    const float* e8a_w      = (const float*)d_in[18];
    const float* e8a_b      = (const float*)d_in[19];
    const float* e8b_w      = (const float*)d_in[20];
    const float* e8b_b      = (const float*)d_in[21];
    const float* codebook   = (const float*)d_in[22];

    float* out = (float*)d_out;
    float* y_out     = out;                        // [B,T,256]
    float* codes_out = out + (size_t)MTOK * 256;   // [B,T,8]
    float* idx_out   = codes_out + (size_t)MTOK * 8;
    float* bif_out   = idx_out + MTOK;

    // ---- workspace layout (G=1, heavy aliasing; ~200 MiB total) ----
    const size_t AL = 255;
    #define ALN(x) (((x) + AL) & ~AL)
    char* p = (char*)d_ws;
    #define TAKE(T, name, bytes) T* name = (T*)p; p += ALN((size_t)(bytes));
    TAKE(float, risk, MTOK * 4)
    TAKE(float, vn,   MTOK * 4)
    TAKE(u16, wiTh, (size_t)1024 * 256 * 2)
    TAKE(u16, wiTl, (size_t)1024 * 256 * 2)
    TAKE(u16, wcTh, (size_t)512 * 512 * 2)
    TAKE(u16, wcTl, (size_t)512 * 512 * 2)
    TAKE(u16, wdbTh, (size_t)640 * 512 * 2)
    TAKE(u16, wdbTl, (size_t)640 * 512 * 2)
    TAKE(u16, woTh, (size_t)256 * 512 * 2)
    TAKE(u16, woTl, (size_t)256 * 512 * 2)
    TAKE(u16, whTh, (size_t)128 * 256 * 2)
    TAKE(u16, whTl, (size_t)128 * 256 * 2)
    TAKE(float, dbbias, 640 * 4)
    TAKE(float, hbias, 128 * 4)
    TAKE(u16, A0, (size_t)2 * MTOK * 512 * 2)   // region A: 64 MiB
    TAKE(u16, B0, (size_t)2 * MTOK * 512 * 2)   // region B: 64 MiB
    TAKE(float, GATE, (size_t)MTOK * 512 * 4)   // 64 MiB
    TAKE(float, BC, (size_t)MTOK * 32 * 4)      // 4 MiB

    // region A: MAIN planes -> DT f32 -> y planes
    u16* MAINh = A0;
    u16* MAINl = A0 + (size_t)MTOK * 512;
    float* DT  = (float*)A0;
    u16* yh    = A0;
    u16* yl    = A0 + (size_t)MTOK * 512;
    // region B: x planes -> XC planes -> YG planes (in-place)
    u16* xh  = B0;
    u16* xl  = B0 + (size_t)MTOK * 512;
    u16* XCh = B0;
    u16* XCl = B0 + (size_t)MTOK * 512;
    // GATE -> F1
    float* F1 = GATE;
    // P/H live in d_out's y slab (exactly 2 x 16.78MB), overwritten by out_proj
    float* Pb = y_out;
    float* Hb = y_out + (size_t)MTOK * 128;

    // ---- prep ----
    split_kernel<<<(MTOK * 256 + 255) / 256, 256, 0, stream>>>(x, xh, xl, MTOK * 256);
    prep_weights<<<(1016576 + 255) / 256, 256, 0, stream>>>(
        in_proj_w, conv_w, dt_w, bc_w, out_w, cat1_w, e8a_w,
        dt_b, bc_b, cat1_b, e8a_b,
        wiTh, wiTl, wcTh, wcTl, wdbTh, wdbTl, woTh, woTl, whTh, whTl,
        dbbias, hbias);

    // ---- pipeline, full batch (XCD-aware mapping) ----
    // 1. in_proj -> MAIN planes + GATE f32
    gemmS<0, 8><<<256 * 8, 256, 0, stream>>>(
        xh, xl, 256, wiTh, wiTl, in_proj_b, GATE, nullptr, MAINh, MAINl);
    // 2. conv: silu -> XC planes (over x planes)
    gemmS<1, 4><<<256 * 4, 256, 0, stream>>>(
        MAINh, MAINl, 512, wcTh, wcTl, conv_b, nullptr, nullptr, XCh, XCl);
    // 3. dt+bc fused: softplus -> DT f32 (over MAIN), raw -> BC
    gemmS<2, 5><<<256 * 5, 256, 0, stream>>>(
        XCh, XCl, 512, wdbTh, wdbTl, dbbias, DT, BC, nullptr, nullptr);
    // 4-6. chunked scan; P/H in d_out y slab; YG in place over XC
    scan_pass1<<<BB * SCAN_NC * 2, 256, 0, stream>>>(DT, XCh, XCl, BC, A_log, Pb, Hb);
    scan_pass2<<<256, 256, 0, stream>>>(Pb, Hb);
    scan_pass3<<<BB * SCAN_NC * 2, 256, 0, stream>>>(DT, XCh, XCl, BC, A_log, GATE,
                                                     Hb, XCh, XCl);
    // 7. out_proj (64-row tiles, 1024 blocks) -> y f32 (over P/H) + y planes (over DT)
    gemmS64<4, 2><<<512 * 2, 256, 0, stream>>>(
        XCh, XCl, 512, woTh, woTl, out_b, y_out, yh, yl);
    // 8. head layer-1 (64-row tiles, 512 blocks) -> F1 (over GATE)
    gemmS64<5, 1><<<512 * 1, 256, 0, stream>>>(
        yh, yl, 256, whTh, whTl, hbias, F1, nullptr, nullptr);
    // 9. finishers
    head_finish<<<MTOK / 64, 256, 0, stream>>>(F1, cat2_w, cat2_b, risk_w, risk_b,
                                               e8b_w, e8b_b, codebook,
                                               risk, codes_out, idx_out);
    vn_kernel<<<MTOK / 4, 256, 0, stream>>>(y_out, vn);
    combined_kernel<<<MTOK / 256, 256, 0, stream>>>(risk, vn, bif_out);
}

// Round 10
// 685.529 us; speedup vs baseline: 1.2989x; 1.0060x over previous
//
#include <hip/hip_runtime.h>
#include <hip/hip_bf16.h>
#include <math.h>

// Problem dims
#define BB 8
#define TT 4096
#define DD 256
#define INNER 512
#define SS 16
#define MTOK (BB*TT)          // 32768 tokens
#define NCODE 240

#define SCAN_NC 64
#define SCAN_L  64            // TT / SCAN_NC

typedef unsigned short u16;
typedef unsigned int   u32;
typedef __attribute__((ext_vector_type(8))) short short8;   // 8 bf16 (4 VGPRs)
typedef __attribute__((ext_vector_type(4))) float f32x4;    // 4 fp32 acc

__device__ __forceinline__ float sigmoidf_(float x) { return 1.f / (1.f + expf(-x)); }
__device__ __forceinline__ float siluf_(float x)    { return x / (1.f + expf(-x)); }
__device__ __forceinline__ float geluf_(float x) {
    float x3 = x * x * x;
    return 0.5f * x * (1.f + tanhf(0.7978845608028654f * (x + 0.044715f * x3)));
}
__device__ __forceinline__ float softplusf_(float x) {
    return fmaxf(x, 0.f) + log1pf(expf(-fabsf(x)));
}

// bf16 round-to-nearest-even helpers (used in prep kernels)
__device__ __forceinline__ u16 f2bf(float v) {
    u32 u = __float_as_uint(v);
    u32 r = (u + 0x7FFFu + ((u >> 16) & 1u)) >> 16;
    return (u16)r;
}
__device__ __forceinline__ float bf2f(u16 h) {
    return __uint_as_float(((u32)h) << 16);
}

// pack high-16-bits of two floats: low u16 = a's hi16, high u16 = b's hi16
__device__ __forceinline__ u32 packhi2(float a, float b) {
    return __builtin_amdgcn_perm(__float_as_uint(b), __float_as_uint(a), 0x07060302u);
}

// trunc-split 4 values into hi/lo planes (2x 8B stores)
__device__ __forceinline__ void store_planes(u16* __restrict__ oh, u16* __restrict__ ol,
                                             size_t off, float v0, float v1, float v2, float v3)
{
    uint2 H;
    H.x = packhi2(v0, v1);
    H.y = packhi2(v2, v3);
    float r0 = v0 - __uint_as_float(__float_as_uint(v0) & 0xFFFF0000u);
    float r1 = v1 - __uint_as_float(__float_as_uint(v1) & 0xFFFF0000u);
    float r2 = v2 - __uint_as_float(__float_as_uint(v2) & 0xFFFF0000u);
    float r3 = v3 - __uint_as_float(__float_as_uint(v3) & 0xFFFF0000u);
    uint2 L;
    L.x = packhi2(r0, r1);
    L.y = packhi2(r2, r3);
    *(uint2*)(oh + off) = H;
    *(uint2*)(ol + off) = L;
}

__device__ __forceinline__ void gload16(const void* g, void* l) {
    __builtin_amdgcn_global_load_lds((const __attribute__((address_space(1))) u32*)g,
                                     (__attribute__((address_space(3))) u32*)l, 16, 0, 0);
}

// ---------------------------------------------------------------------------
// Split-bf16 MFMA GEMM, 128x128 tile (4 waves, 64x64/wave).
// OPERAND-SWAPPED: mfma(W_frag, X_frag) -> D[wcol][token]; each thread's 4
// acc regs = 4 CONSECUTIVE output columns of one token -> vector stores.
// MODE: 0=in_proj (cols<512 -> MAIN planes, cols>=512 -> GATE f32)
//       1=conv   (silu -> XC planes)
//       2=dt+bc  (cols<512 softplus -> DT f32; cols 512..543 -> BC f32)
// CT = N/128. XCD-aware (T1): xcd=i&7 owns 32 row-tiles; col fastest within XCD.
// ---------------------------------------------------------------------------
template<int MODE, int CT>
__global__ __launch_bounds__(256)
void gemmS(const u16* __restrict__ Ah, const u16* __restrict__ Al, int K,
           const u16* __restrict__ BTh, const u16* __restrict__ BTl,
           const float* __restrict__ bias,
           float* __restrict__ out0, float* __restrict__ out1,
           u16* __restrict__ oh, u16* __restrict__ ol)
{
    __shared__ u16 sm[4][128 * 32];   // Xh, Xl, Wh, Wl tiles: 8KB each

    const int tid  = threadIdx.x;
    const int lane = tid & 63;
    const int wv   = tid >> 6;
    const int wr   = wv >> 1;          // 0..1 (token half)
    const int wc   = wv & 1;           // 0..1 (col half)
    const int lc   = lane & 15;
    const int kc   = lane >> 4;        // 0..3 (k-chunk of 8)

    const int i    = blockIdx.x;
    const int xcd  = i & 7;
    const int j    = i >> 3;
    const int row0 = (xcd * 32 + j / CT) * 128;
    const int col0 = (j % CT) * 128;

    const u16* Agh = Ah + (size_t)row0 * K;
    const u16* Agl = Al + (size_t)row0 * K;
    const u16* Bgh = BTh + (size_t)col0 * K;
    const u16* Bgl = BTl + (size_t)col0 * K;

    f32x4 acc[4][4];
    #pragma unroll
    for (int m = 0; m < 4; ++m)
        #pragma unroll
        for (int n = 0; n < 4; ++n) acc[m][n] = (f32x4)0.f;

    for (int k0 = 0; k0 < K; k0 += 32) {
        #pragma unroll
        for (int c = 0; c < 2; ++c) {
            int e = c * 256 + tid;
            int row = e >> 2, ch = e & 3;
            int chs = ch ^ ((row >> 1) & 3);
            size_t go = (size_t)row * K + k0 + chs * 8;
            gload16(Agh + go, &sm[0][e * 8]);
            gload16(Agl + go, &sm[1][e * 8]);
            gload16(Bgh + go, &sm[2][e * 8]);
            gload16(Bgl + go, &sm[3][e * 8]);
        }
        __syncthreads();

        short8 ah[4], al[4], bh[4], bl[4];
        #pragma unroll
        for (int m = 0; m < 4; ++m) {
            int row = wr * 64 + m * 16 + lc;
            int off = row * 32 + ((kc ^ ((row >> 1) & 3)) << 3);
            ah[m] = *(const short8*)&sm[0][off];
            al[m] = *(const short8*)&sm[1][off];
        }
        #pragma unroll
        for (int n = 0; n < 4; ++n) {
            int row = wc * 64 + n * 16 + lc;
            int off = row * 32 + ((kc ^ ((row >> 1) & 3)) << 3);
            bh[n] = *(const short8*)&sm[2][off];
            bl[n] = *(const short8*)&sm[3][off];
        }
        // swapped: weight frag first -> D rows = weight cols
        #pragma unroll
        for (int m = 0; m < 4; ++m)
            #pragma unroll
            for (int n = 0; n < 4; ++n) {
                acc[m][n] = __builtin_amdgcn_mfma_f32_16x16x32_bf16(bh[n], ah[m], acc[m][n], 0, 0, 0);
                acc[m][n] = __builtin_amdgcn_mfma_f32_16x16x32_bf16(bl[n], ah[m], acc[m][n], 0, 0, 0);
                acc[m][n] = __builtin_amdgcn_mfma_f32_16x16x32_bf16(bh[n], al[m], acc[m][n], 0, 0, 0);
            }
        __syncthreads();
    }

    // epilogue: thread owns token = row-side + lc, cols colq..colq+3 per acc
    #pragma unroll
    for (int n = 0; n < 4; ++n) {
        const int colq = col0 + wc * 64 + n * 16 + kc * 4;
        const float4 bv = *(const float4*)&bias[colq];
        #pragma unroll
        for (int m = 0; m < 4; ++m) {
            f32x4 a = acc[m][n];
            const int token = row0 + wr * 64 + m * 16 + lc;
            float v0 = a[0] + bv.x, v1 = a[1] + bv.y, v2 = a[2] + bv.z, v3 = a[3] + bv.w;
            if (MODE == 0) {
                if (colq < 512) {
                    store_planes(oh, ol, (size_t)token * 512 + colq, v0, v1, v2, v3);
                } else {
                    *(float4*)&out0[(size_t)token * 512 + colq - 512] =
                        make_float4(v0, v1, v2, v3);   // gate f32
                }
            } else if (MODE == 1) {
                v0 = siluf_(v0); v1 = siluf_(v1); v2 = siluf_(v2); v3 = siluf_(v3);
                store_planes(oh, ol, (size_t)token * 512 + colq, v0, v1, v2, v3);
            } else {  // MODE 2
                if (colq < 512) {
                    *(float4*)&out0[(size_t)token * 512 + colq] =
                        make_float4(softplusf_(v0), softplusf_(v1),
                                    softplusf_(v2), softplusf_(v3));   // DT
                } else if (colq < 544) {
                    *(float4*)&out1[(size_t)token * 32 + colq - 512] =
                        make_float4(v0, v1, v2, v3);                   // BC
                }
            }
        }
    }
}

// ---------------------------------------------------------------------------
// Split-bf16 MFMA GEMM, 64x128 tile (4 waves, 16 tokens x 128 cols per wave).
// Operand-swapped like gemmS. MODE: 4=out (y f32 + y planes), 5=head (gelu->F1)
// ---------------------------------------------------------------------------
template<int MODE, int CT>
__global__ __launch_bounds__(256)
void gemmS64(const u16* __restrict__ Ah, const u16* __restrict__ Al, int K,
             const u16* __restrict__ BTh, const u16* __restrict__ BTl,
             const float* __restrict__ bias,
             float* __restrict__ out0, u16* __restrict__ oh, u16* __restrict__ ol)
{
    __shared__ u16 smA[2][64 * 32];    // token planes: 4KB each
    __shared__ u16 smB[2][128 * 32];   // weight planes: 8KB each

    const int tid  = threadIdx.x;
    const int lane = tid & 63;
    const int wv   = tid >> 6;         // 0..3: wave's 16-token strip
    const int lc   = lane & 15;
    const int kc   = lane >> 4;        // 0..3

    const int i    = blockIdx.x;
    const int xcd  = i & 7;
    const int j    = i >> 3;
    const int row0 = (xcd * 64 + j / CT) * 64;
    const int col0 = (j % CT) * 128;

    const u16* Agh = Ah + (size_t)row0 * K;
    const u16* Agl = Al + (size_t)row0 * K;
    const u16* Bgh = BTh + (size_t)col0 * K;
    const u16* Bgl = BTl + (size_t)col0 * K;

    f32x4 acc[8];
    #pragma unroll
    for (int n = 0; n < 8; ++n) acc[n] = (f32x4)0.f;

    for (int k0 = 0; k0 < K; k0 += 32) {
        {   // stage tokens: 64 rows x 4 chunks = 256 vectors
            int e = tid;
            int row = e >> 2, ch = e & 3;
            int chs = ch ^ ((row >> 1) & 3);
            size_t go = (size_t)row * K + k0 + chs * 8;
            gload16(Agh + go, &smA[0][e * 8]);
            gload16(Agl + go, &smA[1][e * 8]);
        }
        #pragma unroll
        for (int c = 0; c < 2; ++c) {   // stage weights: 128 rows x 4 chunks
            int e = c * 256 + tid;
            int row = e >> 2, ch = e & 3;
            int chs = ch ^ ((row >> 1) & 3);
            size_t go = (size_t)row * K + k0 + chs * 8;
            gload16(Bgh + go, &smB[0][e * 8]);
            gload16(Bgl + go, &smB[1][e * 8]);
        }
        __syncthreads();

        short8 ah, al;
        {
            int row = wv * 16 + lc;
            int off = row * 32 + ((kc ^ ((row >> 1) & 3)) << 3);
            ah = *(const short8*)&smA[0][off];
            al = *(const short8*)&smA[1][off];
        }
        #pragma unroll
        for (int n = 0; n < 8; ++n) {
            int row = n * 16 + lc;
            int off = row * 32 + ((kc ^ ((row >> 1) & 3)) << 3);
            short8 bh = *(const short8*)&smB[0][off];
            short8 bl = *(const short8*)&smB[1][off];
            acc[n] = __builtin_amdgcn_mfma_f32_16x16x32_bf16(bh, ah, acc[n], 0, 0, 0);
            acc[n] = __builtin_amdgcn_mfma_f32_16x16x32_bf16(bl, ah, acc[n], 0, 0, 0);
            acc[n] = __builtin_amdgcn_mfma_f32_16x16x32_bf16(bh, al, acc[n], 0, 0, 0);
        }
        __syncthreads();
    }

    const int token = row0 + wv * 16 + lc;
    #pragma unroll
    for (int n = 0; n < 8; ++n) {
        const int colq = col0 + n * 16 + kc * 4;
        const float4 bv = *(const float4*)&bias[colq];
        f32x4 a = acc[n];
        float v0 = a[0] + bv.x, v1 = a[1] + bv.y, v2 = a[2] + bv.z, v3 = a[3] + bv.w;
        if (MODE == 4) {
            *(float4*)&out0[(size_t)token * 256 + colq] = make_float4(v0, v1, v2, v3);
            store_planes(oh, ol, (size_t)token * 256 + colq, v0, v1, v2, v3);
        } else {  // MODE 5: head layer-1, gelu
            *(float4*)&out0[(size_t)token * 128 + colq] =
                make_float4(geluf_(v0), geluf_(v1), geluf_(v2), geluf_(v3));
        }
    }
}

// ---------------------------------------------------------------------------
// Conversion / prep kernels
// ---------------------------------------------------------------------------
__global__ __launch_bounds__(256)
void split_kernel(const float* __restrict__ s, u16* __restrict__ h,
                  u16* __restrict__ l, int n)
{
    int i = blockIdx.x * 256 + threadIdx.x;
    if (i >= n) return;
    float v = s[i];
    u16 hh = f2bf(v);
    h[i] = hh;
    l[i] = f2bf(v - bf2f(hh));
}

// All weight transposes/splits + fused dt|bc and cat1|e8a concats, one launch.
__global__ __launch_bounds__(256)
void prep_weights(const float* __restrict__ in_proj_w, const float* __restrict__ conv_w,
                  const float* __restrict__ dt_w, const float* __restrict__ bc_w,
                  const float* __restrict__ out_w,
                  const float* __restrict__ cat1_w, const float* __restrict__ e8a_w,
                  const float* __restrict__ dt_b, const float* __restrict__ bc_b,
                  const float* __restrict__ cat1_b, const float* __restrict__ e8a_b,
                  u16* __restrict__ wiTh, u16* __restrict__ wiTl,
                  u16* __restrict__ wcTh, u16* __restrict__ wcTl,
                  u16* __restrict__ wdbTh, u16* __restrict__ wdbTl,
                  u16* __restrict__ woTh, u16* __restrict__ woTl,
                  u16* __restrict__ whTh, u16* __restrict__ whTl,
                  float* __restrict__ dbbias, float* __restrict__ hbias)
{
    int idx = blockIdx.x * 256 + threadIdx.x;
    float v; u16 *dh, *dl; int off;
    if (idx < 262144) {                       // in_projT [1024][256]
        int e = idx, n = e >> 8, k = e & 255;
        v = in_proj_w[(size_t)k * 1024 + n]; dh = wiTh; dl = wiTl; off = e;
    } else if (idx < 524288) {                // convT [512][512]
        int e = idx - 262144, n = e >> 9, k = e & 511;
        v = conv_w[(size_t)k * 512 + n]; dh = wcTh; dl = wcTl; off = e;
    } else if (idx < 851968) {                // dt|bc T [640][512]
        int e = idx - 524288, n = e >> 9, k = e & 511;
        v = (n < 512) ? dt_w[(size_t)k * 512 + n]
                      : ((n < 544) ? bc_w[(size_t)k * 32 + (n - 512)] : 0.f);
        dh = wdbTh; dl = wdbTl; off = e;
    } else if (idx < 983040) {                // outT [256][512]
        int e = idx - 851968, n = e >> 9, k = e & 511;
        v = out_w[(size_t)k * 256 + n]; dh = woTh; dl = woTl; off = e;
    } else if (idx < 1015808) {               // headT [128][256]
        int e = idx - 983040, n = e >> 8, k = e & 255;
        v = (n < 64) ? cat1_w[(size_t)k * 64 + n] : e8a_w[(size_t)k * 64 + (n - 64)];
        dh = whTh; dl = whTl; off = e;
    } else if (idx < 1015808 + 640) {
        int i = idx - 1015808;
        dbbias[i] = (i < 512) ? dt_b[i] : ((i < 544) ? bc_b[i - 512] : 0.f);
        return;
    } else if (idx < 1015808 + 640 + 128) {
        int i = idx - 1015808 - 640;
        hbias[i] = (i < 64) ? cat1_b[i] : e8a_b[i - 64];
        return;
    } else return;
    u16 hh = f2bf(v); dh[off] = hh; dl[off] = f2bf(v - bf2f(hh));
}

// ---------------------------------------------------------------------------
// Selective scan, register-state design. Full batch: grid 1024 blocks.
// ---------------------------------------------------------------------------
__global__ __launch_bounds__(256)
void scan_pass1(const float* __restrict__ DT, const u16* __restrict__ XCh,
                const u16* __restrict__ XCl, const float* __restrict__ BC,
                const float* __restrict__ A_log,
                float* __restrict__ Pbuf, float* __restrict__ Hbuf)
{
    const int bid  = blockIdx.x;
    const int half = bid & 1;
    const int c    = (bid >> 1) & (SCAN_NC - 1);
    const int b    = bid >> 7;
    const int ch   = half * 256 + threadIdx.x;
    const int row0 = b * TT + c * SCAN_L;

    float A[16];
    {
        const float4* ar = (const float4*)(A_log + ch * 16);
        #pragma unroll
        for (int q = 0; q < 4; ++q) {
            float4 v = ar[q];
            A[q * 4 + 0] = -__expf(v.x);
            A[q * 4 + 1] = -__expf(v.y);
            A[q * 4 + 2] = -__expf(v.z);
            A[q * 4 + 3] = -__expf(v.w);
        }
    }

    float h[16];
    #pragma unroll
    for (int s = 0; s < 16; ++s) h[s] = 0.f;
    float dtsum = 0.f;

    const float* dtp = DT  + (size_t)row0 * 512 + ch;
    const u16*   xhp = XCh + (size_t)row0 * 512 + ch;
    const u16*   xlp = XCl + (size_t)row0 * 512 + ch;
    const float* bcp = BC  + (size_t)row0 * 32;

    float dv = dtp[0];
    float xv = bf2f(xhp[0]) + bf2f(xlp[0]);
    for (int t = 0; t < SCAN_L; ++t) {
        const int tn = (t + 1 < SCAN_L) ? t + 1 : t;
        float dvn = dtp[(size_t)tn * 512];
        float xvn = bf2f(xhp[(size_t)tn * 512]) + bf2f(xlp[(size_t)tn * 512]);
        const float* br = bcp + (size_t)t * 32;   // wave-uniform row
        float dtx = dv * xv;
        dtsum += dv;
        #pragma unroll
        for (int s = 0; s < 16; ++s) {
            float a = __expf(dv * A[s]);
            h[s] = fmaf(a, h[s], dtx * br[s]);
        }
        dv = dvn; xv = xvn;
    }

    size_t o = ((size_t)(b * SCAN_NC + c) * 512 + ch) * 16;
    #pragma unroll
    for (int s = 0; s < 16; ++s) {
        Pbuf[o + s] = __expf(dtsum * A[s]);
        Hbuf[o + s] = h[s];
    }
}

__global__ __launch_bounds__(256)
void scan_pass2(const float* __restrict__ Pbuf, float* __restrict__ Hbuf)
{
    const int idx = blockIdx.x * 256 + threadIdx.x;   // 65536 threads
    const int b = idx >> 13;
    const int ds = idx & 8191;
    float hin = 0.f;
    for (int c = 0; c < SCAN_NC; ++c) {
        size_t o = ((size_t)(b * SCAN_NC + c)) * (INNER * SS) + ds;
        float p = Pbuf[o], hh = Hbuf[o];
        Hbuf[o] = hin;
        hin = fmaf(p, hin, hh);
    }
}

// pass3 writes YG planes IN PLACE over XC planes (same thread column,
// read[t+1]-before-write[t]; tail read is dead).
__global__ __launch_bounds__(256)
void scan_pass3(const float* __restrict__ DT, const u16* __restrict__ XCh,
                const u16* __restrict__ XCl, const float* __restrict__ BC,
                const float* __restrict__ A_log, const float* __restrict__ GATE,
                const float* __restrict__ Hin,
                u16* __restrict__ YGh, u16* __restrict__ YGl)
{
    const int bid  = blockIdx.x;
    const int half = bid & 1;
    const int c    = (bid >> 1) & (SCAN_NC - 1);
    const int b    = bid >> 7;
    const int ch   = half * 256 + threadIdx.x;
    const int row0 = b * TT + c * SCAN_L;

    float A[16];
    {
        const float4* ar = (const float4*)(A_log + ch * 16);
        #pragma unroll
        for (int q = 0; q < 4; ++q) {
            float4 v = ar[q];
            A[q * 4 + 0] = -__expf(v.x);
            A[q * 4 + 1] = -__expf(v.y);
            A[q * 4 + 2] = -__expf(v.z);
            A[q * 4 + 3] = -__expf(v.w);
        }
    }

    float h[16];
    {
        size_t o = ((size_t)(b * SCAN_NC + c) * 512 + ch) * 16;
        const float4* hr = (const float4*)(Hin + o);
        #pragma unroll
        for (int q = 0; q < 4; ++q) {
            float4 v = hr[q];
            h[q * 4 + 0] = v.x; h[q * 4 + 1] = v.y;
            h[q * 4 + 2] = v.z; h[q * 4 + 3] = v.w;
        }
    }

    const float* dtp = DT   + (size_t)row0 * 512 + ch;
    const u16*   xhp = XCh  + (size_t)row0 * 512 + ch;
    const u16*   xlp = XCl  + (size_t)row0 * 512 + ch;
    const float* gtp = GATE + (size_t)row0 * 512 + ch;
    const float* bcp = BC   + (size_t)row0 * 32;
    u16* yhp = YGh + (size_t)row0 * 512 + ch;
    u16* ylp = YGl + (size_t)row0 * 512 + ch;

    float dv = dtp[0];
    float xv = bf2f(xhp[0]) + bf2f(xlp[0]);
    float gv = gtp[0];
    for (int t = 0; t < SCAN_L; ++t) {
        const int tn = (t + 1 < SCAN_L) ? t + 1 : t;
        float dvn = dtp[(size_t)tn * 512];
        float xvn = bf2f(xhp[(size_t)tn * 512]) + bf2f(xlp[(size_t)tn * 512]);
        float gvn = gtp[(size_t)tn * 512];
        const float* br = bcp + (size_t)t * 32;   // B=[0..15], C=[16..31]
        float dtx = dv * xv;
        float y = 0.f;
        #pragma unroll
        for (int s = 0; s < 16; ++s) {
            float a = __expf(dv * A[s]);
            h[s] = fmaf(a, h[s], dtx * br[s]);
            y = fmaf(h[s], br[16 + s], y);
        }
        float yg = y * siluf_(gv);
        u16 hh = f2bf(yg);
        yhp[(size_t)t * 512] = hh;
        ylp[(size_t)t * 512] = f2bf(yg - bf2f(hh));
        dv = dvn; xv = xvn; gv = gvn;
    }
}

// ---------------------------------------------------------------------------
// Head finisher (unchanged)
// ---------------------------------------------------------------------------
__global__ __launch_bounds__(256)
void head_finish(const float* __restrict__ F1,
                 const float* __restrict__ w2, const float* __restrict__ b2,
                 const float* __restrict__ w3, const float* __restrict__ b3,
                 const float* __restrict__ wb, const float* __restrict__ bb,
                 const float* __restrict__ cb,
                 float* __restrict__ risk, float* __restrict__ codes_out,
                 float* __restrict__ idx_out)
{
    __shared__ float F1s[64][129];
    __shared__ float w2S[64 * 32];
    __shared__ float wbS[64 * 8];
    __shared__ float cbS[NCODE * 8];
    __shared__ float cnS[NCODE];
    __shared__ float w3S[32];
    __shared__ float b2S[32];
    __shared__ float bbS[8];
    const int tid = threadIdx.x;
    const int tok0 = blockIdx.x * 64;

    for (int e = tid; e < 64 * 128; e += 256)
        F1s[e >> 7][e & 127] = F1[(size_t)tok0 * 128 + e];
    for (int e = tid; e < 64 * 32; e += 256) w2S[e] = w2[e];
    for (int e = tid; e < 64 * 8; e += 256) wbS[e] = wb[e];
    for (int e = tid; e < NCODE * 8; e += 256) cbS[e] = cb[e];
    if (tid < 32) { w3S[tid] = w3[tid]; b2S[tid] = b2[tid]; }
    if (tid < 8) bbS[tid] = bb[tid];
    __syncthreads();
    for (int e = tid; e < NCODE; e += 256) {
        float s = 0.f;
        #pragma unroll
        for (int q = 0; q < 8; ++q) s = fmaf(cbS[e * 8 + q], cbS[e * 8 + q], s);
        cnS[e] = s;
    }
    __syncthreads();

    const int lane = tid & 63;
    const int wv   = tid >> 6;
    const int tl   = wv * 16 + (lane >> 2);
    const int role = lane & 3;
    const float* f1c = &F1s[tl][0];
    const float* f1e = &F1s[tl][64];

    float v = 0.f;
    float bd = 3.4e38f;
    int bi = 0;

    if (role < 2) {
        float f2[16];
        #pragma unroll
        for (int d = 0; d < 16; ++d) f2[d] = b2S[role * 16 + d];
        for (int k = 0; k < 64; ++k) {
            float fv = f1c[k];
            #pragma unroll
            for (int d = 0; d < 16; ++d)
                f2[d] = fmaf(fv, w2S[k * 32 + role * 16 + d], f2[d]);
        }
        #pragma unroll
        for (int d = 0; d < 16; ++d) v = fmaf(f2[d], w3S[role * 16 + d], v);
    } else {
        float ec[8];
        #pragma unroll
        for (int q = 0; q < 8; ++q) ec[q] = bbS[q];
        for (int k = 0; k < 64; ++k) {
            float fv = f1e[k];
            #pragma unroll
            for (int q = 0; q < 8; ++q) ec[q] = fmaf(fv, wbS[k * 8 + q], ec[q]);
        }
        float fn = 0.f;
        #pragma unroll
        for (int q = 0; q < 8; ++q) fn = fmaf(ec[q], ec[q], fn);
        const int base = (role - 2) * 120;
        for (int i = 0; i < 120; ++i) {
            int cc = base + i;
            float dot = 0.f;
            #pragma unroll
            for (int q = 0; q < 8; ++q) dot = fmaf(ec[q], cbS[cc * 8 + q], dot);
            float d = fn + cnS[cc] - 2.f * dot;
            if (d < bd) { bd = d; bi = cc; }
        }
    }

    float vp = __shfl_xor(v, 1, 64);
    float od = __shfl_xor(bd, 1, 64);
    int   oi = __shfl_xor(bi, 1, 64);
    const int tok = tok0 + tl;
    if (role == 0) risk[tok] = sigmoidf_(v + vp + b3[0]);
    if (role == 2) {
        if (od < bd || (od == bd && oi < bi)) { bd = od; bi = oi; }
        idx_out[tok] = (float)bi;
        #pragma unroll
        for (int q = 0; q < 8; ++q)
            codes_out[(size_t)tok * 8 + q] = cbS[bi * 8 + q];
    }
}

// ---------------------------------------------------------------------------
__global__ __launch_bounds__(256)
void vn_kernel(const float* __restrict__ y, float* __restrict__ vn)
{
    const int tid = threadIdx.x;
    const int w = tid >> 6, j = tid & 63;
    const int t = blockIdx.x * 4 + w;
    const int tt = t & (TT - 1);
    const float4* cur = (const float4*)(y + (size_t)t * 256);
    const float4* prv = (const float4*)(y + (size_t)(tt == 0 ? t : t - 1) * 256);
    float4 a = cur[j], b = prv[j];
    float dx = a.x - b.x, dy = a.y - b.y, dz = a.z - b.z, dw = a.w - b.w;
    float ss = dx * dx + dy * dy + dz * dz + dw * dw;
    ss += __shfl_xor(ss, 1, 64);
    ss += __shfl_xor(ss, 2, 64);
    ss += __shfl_xor(ss, 4, 64);
    ss += __shfl_xor(ss, 8, 64);
    ss += __shfl_xor(ss, 16, 64);
    ss += __shfl_xor(ss, 32, 64);
    if (j == 0) vn[t] = sqrtf(ss);
}

__global__ __launch_bounds__(256)
void combined_kernel(const float* __restrict__ risk, const float* __restrict__ vn,
                     float* __restrict__ bif)
{
    const int t = blockIdx.x * 256 + threadIdx.x;
    const int tt = t & (TT - 1);
    float v = vn[t];
    float a = (tt == 0) ? 0.f : fabsf(v - vn[t - 1]);
    float cmb = 0.5f * risk[t] + 0.3f * sigmoidf_(v) + 0.2f * sigmoidf_(a);
    bif[t] = (cmb > 0.7f) ? 1.f : 0.f;
}

// ---------------------------------------------------------------------------
extern "C" void kernel_launch(void* const* d_in, const int* in_sizes, int n_in,
                              void* d_out, int out_size, void* d_ws, size_t ws_size,
                              hipStream_t stream)
{
    const float* x          = (const float*)d_in[0];
    const float* in_proj_w  = (const float*)d_in[1];
    const float* in_proj_b  = (const float*)d_in[2];
    const float* conv_w     = (const float*)d_in[3];
    const float* conv_b     = (const float*)d_in[4];
    const float* A_log      = (const float*)d_in[5];
    const float* bc_w       = (const float*)d_in[6];
    const float* bc_b       = (const float*)d_in[7];
    const float* dt_w       = (const float*)d_in[8];
    const float* dt_b       = (const float*)d_in[9];
    const float* out_w      = (const float*)d_in[10];
    const float* out_b      = (const float*)d_in[11];
    const float* cat1_w     = (const float*)d_in[12];
    const float* cat1_b     = (const float*)d_in[13];
    const float* cat2_w     = (const float*)d_in[14];
    const float* cat2_b     = (const float*)d_in[15];
    const float* risk_w     = (const float*)d_in[16];
    const float* risk_b     = (const float*)d_in[17];
    const float* e8a_w      = (const float*)d_in[18];
    const float* e8a_b      = (const float*)d_in[19];
    const float* e8b_w      = (const float*)d_in[20];
    const float* e8b_b      = (const float*)d_in[21];
    const float* codebook   = (const float*)d_in[22];

    float* out = (float*)d_out;
    float* y_out     = out;                        // [B,T,256]
    float* codes_out = out + (size_t)MTOK * 256;   // [B,T,8]
    float* idx_out   = codes_out + (size_t)MTOK * 8;
    float* bif_out   = idx_out + MTOK;

    // ---- workspace layout (G=1, heavy aliasing; ~200 MiB total) ----
    const size_t AL = 255;
    #define ALN(x) (((x) + AL) & ~AL)
    char* p = (char*)d_ws;
    #define TAKE(T, name, bytes) T* name = (T*)p; p += ALN((size_t)(bytes));
    TAKE(float, risk, MTOK * 4)
    TAKE(float, vn,   MTOK * 4)
    TAKE(u16, wiTh, (size_t)1024 * 256 * 2)
    TAKE(u16, wiTl, (size_t)1024 * 256 * 2)
    TAKE(u16, wcTh, (size_t)512 * 512 * 2)
    TAKE(u16, wcTl, (size_t)512 * 512 * 2)
    TAKE(u16, wdbTh, (size_t)640 * 512 * 2)
    TAKE(u16, wdbTl, (size_t)640 * 512 * 2)
    TAKE(u16, woTh, (size_t)256 * 512 * 2)
    TAKE(u16, woTl, (size_t)256 * 512 * 2)
    TAKE(u16, whTh, (size_t)128 * 256 * 2)
    TAKE(u16, whTl, (size_t)128 * 256 * 2)
    TAKE(float, dbbias, 640 * 4)
    TAKE(float, hbias, 128 * 4)
    TAKE(u16, A0, (size_t)2 * MTOK * 512 * 2)   // region A: 64 MiB
    TAKE(u16, B0, (size_t)2 * MTOK * 512 * 2)   // region B: 64 MiB
    TAKE(float, GATE, (size_t)MTOK * 512 * 4)   // 64 MiB
    TAKE(float, BC, (size_t)MTOK * 32 * 4)      // 4 MiB

    // region A: MAIN planes -> DT f32 -> y planes
    u16* MAINh = A0;
    u16* MAINl = A0 + (size_t)MTOK * 512;
    float* DT  = (float*)A0;
    u16* yh    = A0;
    u16* yl    = A0 + (size_t)MTOK * 512;
    // region B: x planes -> XC planes -> YG planes (in-place)
    u16* xh  = B0;
    u16* xl  = B0 + (size_t)MTOK * 512;
    u16* XCh = B0;
    u16* XCl = B0 + (size_t)MTOK * 512;
    // GATE -> F1
    float* F1 = GATE;
    // P/H live in d_out's y slab (exactly 2 x 16.78MB), overwritten by out_proj
    float* Pb = y_out;
    float* Hb = y_out + (size_t)MTOK * 128;

    // ---- prep ----
    split_kernel<<<(MTOK * 256 + 255) / 256, 256, 0, stream>>>(x, xh, xl, MTOK * 256);
    prep_weights<<<(1016576 + 255) / 256, 256, 0, stream>>>(
        in_proj_w, conv_w, dt_w, bc_w, out_w, cat1_w, e8a_w,
        dt_b, bc_b, cat1_b, e8a_b,
        wiTh, wiTl, wcTh, wcTl, wdbTh, wdbTl, woTh, woTl, whTh, whTl,
        dbbias, hbias);

    // ---- pipeline, full batch (XCD-aware mapping) ----
    // 1. in_proj -> MAIN planes + GATE f32
    gemmS<0, 8><<<256 * 8, 256, 0, stream>>>(
        xh, xl, 256, wiTh, wiTl, in_proj_b, GATE, nullptr, MAINh, MAINl);
    // 2. conv: silu -> XC planes (over x planes)
    gemmS<1, 4><<<256 * 4, 256, 0, stream>>>(
        MAINh, MAINl, 512, wcTh, wcTl, conv_b, nullptr, nullptr, XCh, XCl);
    // 3. dt+bc fused: softplus -> DT f32 (over MAIN), raw -> BC
    gemmS<2, 5><<<256 * 5, 256, 0, stream>>>(
        XCh, XCl, 512, wdbTh, wdbTl, dbbias, DT, BC, nullptr, nullptr);
    // 4-6. chunked scan; P/H in d_out y slab; YG in place over XC
    scan_pass1<<<BB * SCAN_NC * 2, 256, 0, stream>>>(DT, XCh, XCl, BC, A_log, Pb, Hb);
    scan_pass2<<<256, 256, 0, stream>>>(Pb, Hb);
    scan_pass3<<<BB * SCAN_NC * 2, 256, 0, stream>>>(DT, XCh, XCl, BC, A_log, GATE,
                                                     Hb, XCh, XCl);
    // 7. out_proj (64-row tiles, 1024 blocks) -> y f32 (over P/H) + y planes (over DT)
    gemmS64<4, 2><<<512 * 2, 256, 0, stream>>>(
        XCh, XCl, 512, woTh, woTl, out_b, y_out, yh, yl);
    // 8. head layer-1 (64-row tiles, 512 blocks) -> F1 (over GATE)
    gemmS64<5, 1><<<512 * 1, 256, 0, stream>>>(
        yh, yl, 256, whTh, whTl, hbias, F1, nullptr, nullptr);
    // 9. finishers
    head_finish<<<MTOK / 64, 256, 0, stream>>>(F1, cat2_w, cat2_b, risk_w, risk_b,
                                               e8b_w, e8b_b, codebook,
                                               risk, codes_out, idx_out);
    vn_kernel<<<MTOK / 4, 256, 0, stream>>>(y_out, vn);
    combined_kernel<<<MTOK / 256, 256, 0, stream>>>(risk, vn, bif_out);
}